// Round 14
// baseline (422.838 us; speedup 1.0000x reference)
//
#include <hip/hip_runtime.h>

#define S_LEN 4096
#define DMODEL 1024
#define NHEADS 16

typedef __attribute__((ext_vector_type(8))) short bf16x8;
typedef __attribute__((ext_vector_type(4))) float f32x4;
typedef unsigned short u16;
typedef unsigned int u32;
typedef unsigned long long u64;

// IR+MIR memory fence: pins VMEM issue order at group granularity.
#define MEMFENCE asm volatile("" ::: "memory")

__device__ inline u16 f2bf(float f) {
    union { float f; u32 u; } v; v.f = f;
    u32 r = v.u + 0x7fffu + ((v.u >> 16) & 1u);
    return (u16)(r >> 16);
}

// exact RNE pack (epilogues)
__device__ inline u32 pkbf2(float a, float b) {
    union { float f; u32 u; } ua, ub; ua.f = a; ub.f = b;
    const u32 ra = ua.u + 0x7fffu + ((ua.u >> 16) & 1u);
    const u32 rb = ub.u + 0x7fffu + ((ub.u >> 16) & 1u);
    return __builtin_amdgcn_perm(rb, ra, 0x07060302u);
}

// fast pack: round-half-up (3 VALU ops). Differs from RNE only at exact ties.
// NOTE: v_cvt_pk_bf16_f32 inline-asm failed correctness twice (rounds 7,9);
// its operand->half mapping on gfx950 does not match lo=a/hi=b. Keep pkbf2f.
__device__ inline u32 pkbf2f(float a, float b) {
    union { float f; u32 u; } ua, ub; ua.f = a; ub.f = b;
    const u32 ra = ua.u + 0x8000u;
    const u32 rb = ub.u + 0x8000u;
    return __builtin_amdgcn_perm(rb, ra, 0x07060302u);
}

// async 16B global->LDS DMA. LDS dst = wave-uniform base + lane*16 at all sites.
__device__ inline void cp16(const void* g, void* l) {
    __builtin_amdgcn_global_load_lds(
        (const __attribute__((address_space(1))) unsigned int*)g,
        (__attribute__((address_space(3))) unsigned int*)l, 16, 0, 0);
}

// One launch converts x (4M), wq/wk/wv (-> w3 contiguous), wo (-> wob). 4096 blocks.
__global__ __launch_bounds__(256) void cvt_all(const float* __restrict__ x,
                                               const float* __restrict__ wq,
                                               const float* __restrict__ wk,
                                               const float* __restrict__ wv,
                                               const float* __restrict__ wo,
                                               u16* __restrict__ xb,
                                               u16* __restrict__ w3,
                                               u16* __restrict__ wob) {
    const int b = blockIdx.x;
    const float* s; u16* d; int off;
    const int NW = DMODEL * DMODEL;  // 1M
    if (b < 2048)      { s = x;  d = xb;          off = b * 2048; }
    else if (b < 2560) { s = wq; d = w3;          off = (b - 2048) * 2048; }
    else if (b < 3072) { s = wk; d = w3 + NW;     off = (b - 2560) * 2048; }
    else if (b < 3584) { s = wv; d = w3 + 2 * NW; off = (b - 3072) * 2048; }
    else               { s = wo; d = wob;         off = (b - 3584) * 2048; }
    const int i = off + threadIdx.x * 8;
    const float4 a = *(const float4*)(s + i);
    const float4 c = *(const float4*)(s + i + 4);
    u16 t[8];
    t[0] = f2bf(a.x); t[1] = f2bf(a.y); t[2] = f2bf(a.z); t[3] = f2bf(a.w);
    t[4] = f2bf(c.x); t[5] = f2bf(c.y); t[6] = f2bf(c.z); t[7] = f2bf(c.w);
    *(bf16x8*)(d + i) = *(const bf16x8*)t;
}

// Fused QKV projection: C = x(4096x1024) * W3^T (W3 = [wq;wk;wv] 3072x1024).
// Triple-buffered counted-vmcnt pipeline; coalesced scalar Q/K stores,
// u64 V^T stores (round-13, verified).
// Q pre-scaled by 1/8*log2e. Q,K -> [h][m][c]; V -> [h][c][m].
__global__ __launch_bounds__(256) void gemm_qkv(const u16* __restrict__ A,
                                                const u16* __restrict__ B3,
                                                u16* __restrict__ Qo,
                                                u16* __restrict__ Ko,
                                                u16* __restrict__ Vo) {
    __shared__ __align__(16) u16 As[3][128 * 32];   // 24KB
    __shared__ __align__(16) u16 Bs[3][128 * 32];   // 24KB
    const int tid = threadIdx.x, lane = tid & 63, wave = tid >> 6;
    const int wm = (wave >> 1) * 64, wn = (wave & 1) * 64;
    const int m0 = blockIdx.y * 128, n0 = blockIdx.x * 128;
    const int l15 = lane & 15, quad = lane >> 4;

    f32x4 acc[4][4];
#pragma unroll
    for (int i = 0; i < 4; i++)
#pragma unroll
        for (int j = 0; j < 4; j++) acc[i][j] = (f32x4){0.f, 0.f, 0.f, 0.f};

    const int r0 = tid >> 2, c0 = (tid & 3) * 8;

// one K-step stage (16KB = 4 cp16/thread) into buffer `buf`
#define STAGE_QKV(buf, kkb)                                                        \
    {                                                                              \
        cp16(A + (size_t)(m0 + r0) * 1024 + (kkb) + c0,       As[buf] + r0 * 32 + c0); \
        cp16(A + (size_t)(m0 + r0 + 64) * 1024 + (kkb) + c0,  As[buf] + (r0 + 64) * 32 + c0); \
        cp16(B3 + (size_t)(n0 + r0) * 1024 + (kkb) + c0,      Bs[buf] + r0 * 32 + c0); \
        cp16(B3 + (size_t)(n0 + r0 + 64) * 1024 + (kkb) + c0, Bs[buf] + (r0 + 64) * 32 + c0); \
    }

#define COMPUTE_QKV(cur)                                                           \
    {                                                                              \
        bf16x8 af[4], bfr[4];                                                      \
        _Pragma("unroll")                                                          \
        for (int i = 0; i < 4; i++)                                                \
            af[i] = *(const bf16x8*)(As[cur] + (wm + i * 16 + l15) * 32 + quad * 8); \
        _Pragma("unroll")                                                          \
        for (int j = 0; j < 4; j++)                                                \
            bfr[j] = *(const bf16x8*)(Bs[cur] + (wn + j * 16 + l15) * 32 + quad * 8); \
        _Pragma("unroll")                                                          \
        for (int i = 0; i < 4; i++)                                                \
            _Pragma("unroll")                                                      \
            for (int j = 0; j < 4; j++)                                            \
                acc[i][j] = __builtin_amdgcn_mfma_f32_16x16x32_bf16(af[i], bfr[j], acc[i][j], 0, 0, 0); \
    }

    // prologue: 2 stages in flight (8 cp16/thread)
    STAGE_QKV(0, 0);
    MEMFENCE;
    STAGE_QKV(1, 32);
    MEMFENCE;

    // main loop: 31 steps with counted wait (stage k+1 stays in flight)
    for (int ks = 0; ks < 31; ks++) {
        asm volatile("s_waitcnt vmcnt(4)" ::: "memory");  // my stage(ks) landed
        __builtin_amdgcn_s_barrier();                     // everyone's stage(ks) landed
        __builtin_amdgcn_sched_barrier(0);
        if (ks < 30) {
            STAGE_QKV((ks + 2) % 3, (ks + 2) * 32);       // 2 steps of latency cover
            MEMFENCE;
        }
        COMPUTE_QKV(ks % 3);
    }
    // tail step 31: drain and compute
    asm volatile("s_waitcnt vmcnt(0)" ::: "memory");
    __builtin_amdgcn_s_barrier();
    __builtin_amdgcn_sched_barrier(0);
    COMPUTE_QKV(1);                                       // 31 % 3 == 1
#undef STAGE_QKV
#undef COMPUTE_QKV

    const int which = n0 >> 10;
    const int n0r = n0 & 1023;
    u16* dst = (which == 0) ? Qo : (which == 1) ? Ko : Vo;
    if (which < 2) {
        // coalesced scalar stores: quarter-wave (l15) = 16 consecutive cols (32B)
        const float sc = (which == 0) ? 0.125f * 1.4426950408889634f : 1.0f;
#pragma unroll
        for (int i = 0; i < 4; i++)
#pragma unroll
            for (int j = 0; j < 4; j++) {
                const int col = n0r + wn + j * 16 + l15;
                const int h = col >> 6, c = col & 63;
#pragma unroll
                for (int r = 0; r < 4; r++) {
                    const int row = m0 + wm + i * 16 + quad * 4 + r;
                    dst[(size_t)h * S_LEN * 64 + (size_t)row * 64 + c] = f2bf(acc[i][j][r] * sc);
                }
            }
    } else {
        // V^T: r=0..3 are 4 consecutive u16 in memory -> u64 store (verified r11)
#pragma unroll
        for (int i = 0; i < 4; i++) {
            const int row0 = m0 + wm + i * 16 + quad * 4;
#pragma unroll
            for (int j = 0; j < 4; j++) {
                const int col = n0r + wn + j * 16 + l15;
                const int h = col >> 6, c = col & 63;
                const u32 y0 = pkbf2(acc[i][j][0], acc[i][j][1]);
                const u32 y1 = pkbf2(acc[i][j][2], acc[i][j][3]);
                *(u64*)(dst + (size_t)h * S_LEN * 64 + (size_t)c * S_LEN + row0) =
                    (u64)y0 | ((u64)y1 << 32);
            }
        }
    }
}

// Output projection: C(fp32 [4096][1024]) = y(bf16) * wo^T. Split-M:
// 64x128 tiles, grid 512 (2/CU), BK=64, dbuf single-barrier, swizzled LDS,
// plain coalesced fp32 stores (round-8 form, verified).
__global__ __launch_bounds__(256) void gemm_out(const u16* __restrict__ A,
                                                const u16* __restrict__ B,
                                                float* __restrict__ C) {
    __shared__ __align__(16) u16 As[2][64 * 64];    // swizzled [row][col]
    __shared__ __align__(16) u16 Bs[2][128 * 64];   // swizzled [row][col]
    const int tid = threadIdx.x, lane = tid & 63, wave = tid >> 6;
    const int wm = (wave >> 1) * 32, wn = (wave & 1) * 64;
    const int bx = blockIdx.x;
    const int n0 = (bx & 7) * 128, m0 = (bx >> 3) * 64;
    const int l15 = lane & 15, quad = lane >> 4;
    const int swz = l15 & 7;

    f32x4 acc[2][4];
#pragma unroll
    for (int i = 0; i < 2; i++)
#pragma unroll
        for (int j = 0; j < 4; j++) acc[i][j] = (f32x4){0.f, 0.f, 0.f, 0.f};

#define STAGE_OUT(buf, kb)                                                              \
    {                                                                                   \
        _Pragma("unroll")                                                               \
        for (int q = 0; q < 2; q++) {                                                   \
            const int ch = tid + q * 256;                                               \
            const int ar = ch >> 3, ac = ((ch & 7) ^ (ar & 7)) * 8;                     \
            cp16(A + (size_t)(m0 + ar) * 1024 + (kb) + ac, As[buf] + ch * 8);           \
        }                                                                               \
        _Pragma("unroll")                                                               \
        for (int q = 0; q < 4; q++) {                                                   \
            const int ch = tid + q * 256;                                               \
            const int br = ch >> 3, bc = ((ch & 7) ^ (br & 7)) * 8;                     \
            cp16(B + (size_t)(n0 + br) * 1024 + (kb) + bc, Bs[buf] + ch * 8);           \
        }                                                                               \
    }

    STAGE_OUT(0, 0);
    int cur = 0;
    for (int kk = 0; kk < 1024; kk += 64) {
        __syncthreads();  // drains vmcnt(0): buf[cur] ready, buf[cur^1] reads done
        if (kk + 64 < 1024) STAGE_OUT(cur ^ 1, kk + 64);
#pragma unroll
        for (int h = 0; h < 2; h++) {
            const int cc = (h * 4 + quad) ^ swz;
            bf16x8 af[2], bfr[4];
#pragma unroll
            for (int i = 0; i < 2; i++)
                af[i] = *(const bf16x8*)(As[cur] + (wm + i * 16 + l15) * 64 + cc * 8);
#pragma unroll
            for (int j = 0; j < 4; j++)
                bfr[j] = *(const bf16x8*)(Bs[cur] + (wn + j * 16 + l15) * 64 + cc * 8);
#pragma unroll
            for (int i = 0; i < 2; i++)
#pragma unroll
                for (int j = 0; j < 4; j++)
                    acc[i][j] = __builtin_amdgcn_mfma_f32_16x16x32_bf16(af[i], bfr[j], acc[i][j], 0, 0, 0);
        }
        cur ^= 1;
    }
#undef STAGE_OUT

#pragma unroll
    for (int i = 0; i < 2; i++)
#pragma unroll
        for (int j = 0; j < 4; j++)
#pragma unroll
            for (int r = 0; r < 4; r++) {
                const int row = m0 + wm + i * 16 + quad * 4 + r;
                const int col = n0 + wn + j * 16 + l15;
                C[(size_t)row * 1024 + col] = acc[i][j][r];
            }
}

// Flash attention, causal — round-14: V DIRECT-TO-REGISTER + 4 waves/SIMD.
// Round-13 counters: MfmaUtil 23 + VALUBusy 45 = 68% -> 32% stall at 3
// waves/SIMD, LDS-capped (48KB). V is consumed once/pair and KV is
// L2-resident (2 heads x 1MB per XCD) -> V loads straight from L2 into
// registers at ITERATION TOP (8 x u64/pair; address pattern verified by
// round-2's passing kernel), consumed in PV a full QK+softmax (~400cy)
// later. K keeps the LDS pair-dbuf. LDS 48->32KB, regs ~108 ->
// __launch_bounds__(256,4) = 4 waves/SIMD (+33%); -4 cp16, -8 ds_read,
// -V addr math per pair.
// vmcnt arithmetic (in-order VMEM retirement): steady iter kp outstanding
// after issue = K(kp)4 + K(kp+1)4 + V(kp)8; QK needs K(kp): vmcnt(12);
// PV needs V(kp): vmcnt(4). First iter: +Qf8 oldest -> vmcnt(12) retires
// Qf8+K(0)4 exactly. Diagonal: vmcnt(8) then vmcnt(0). MEMFENCE pins all
// load groups; setprio(1) wraps MFMA clusters (T5, verified round-13).
// Q (pre-scaled by 1/8*log2e), K: [H][S][64] bf16. Vt: [H][64][S] bf16.
// Y: [S][DMODEL] bf16.
__global__ __launch_bounds__(256, 4) void attn(const u16* __restrict__ Q,
                                               const u16* __restrict__ Kh,
                                               const u16* __restrict__ Vt,
                                               u16* __restrict__ Y) {
    __shared__ __align__(16) u16 KW[2][4][2048];  // 32KB: per-wave K pair dbuf
    const int b = blockIdx.x;
    const int head = b & 15;                      // head pinned to XCD (b%8)
    const int jq = 63 - (b >> 4);                 // longest q-tile first
    const int nkt = jq + 1;                       // 64-key tiles this block needs
    const int np = (nkt + 1) >> 1;                // key-tile PAIRS (incl. odd tail)
    const int qa = jq * 64;
    const int tid = threadIdx.x, lane = tid & 63, w = tid >> 6;
    const int l15 = lane & 15, quad = lane >> 4;
    const int swz = l15 & 7;

    const u16* Qp = Q + (size_t)head * S_LEN * 64;
    const u16* Kp = Kh + (size_t)head * S_LEN * 64;
    const u16* Vp = Vt + (size_t)head * 64 * S_LEN;

    // Q fragments: all 64 q-rows in registers (B-operand: n=l15 row, k=quad*8 dims)
    bf16x8 qf[4][2];
#pragma unroll
    for (int qg = 0; qg < 4; qg++)
#pragma unroll
        for (int h = 0; h < 2; h++)
            qf[qg][h] = *(const bf16x8*)(Qp + (size_t)(qa + qg * 16 + l15) * 64 + h * 32 + quad * 8);
    MEMFENCE;   // qf loads are the oldest VMEM group

    f32x4 o[4][4];   // o[dg][qg]: dim = dg*16+quad*4+r, qrow = qg*16+l15
#pragma unroll
    for (int dg = 0; dg < 4; dg++)
#pragma unroll
        for (int qg = 0; qg < 4; qg++) o[dg][qg] = (f32x4){0.f, 0.f, 0.f, 0.f};
    float lp[4] = {0.f, 0.f, 0.f, 0.f};

    const int keyl = w * 16 + quad * 4;           // key-in-tile of this lane's 4 scores

    // walking V pointers (u16 units): wave's 16-key stripe, 4 dim-groups.
    // vf.d[0] = even-tile keys quad*4.., vf.d[1] = odd-tile (+64).
    const u16* vp0 = Vp + (size_t)l15 * S_LEN + w * 16 + quad * 4;
    const u16* vp1 = vp0 + (size_t)16 * S_LEN;
    const u16* vp2 = vp0 + (size_t)32 * S_LEN;
    const u16* vp3 = vp0 + (size_t)48 * S_LEN;

    union PU { u32 d[4]; bf16x8 v; };
    union VU { u64 d[2]; bf16x8 v; };

// Per-wave K stage: one PAIR stripe (rows 0-15 even tile, 16-31 odd), 4 cp16.
// LDS linear (base + lane*16); swizzle via global source: logchunk = (lane&7)^(lane>>3).
#define STAGE_K(buf, kp2)                                                               \
    {                                                                                   \
        _Pragma("unroll")                                                               \
        for (int i = 0; i < 4; i++) {                                                   \
            const int gk = (kp2) * 128 + w * 16 + (i & 1) * 8 + (lane >> 3) + (i >> 1) * 64; \
            const int lc = (lane & 7) ^ (lane >> 3);                                    \
            cp16(Kp + (size_t)gk * 64 + lc * 8, KW[buf][w] + i * 512 + lane * 8);       \
        }                                                                               \
    }

// V direct loads for one pair into named VU set (8 x u64), pointers walk.
#define LOAD_V(V0, V1, V2, V3)                                                          \
    V0.d[0] = *(const u64*)(vp0); V0.d[1] = *(const u64*)(vp0 + 64); vp0 += 128;        \
    V1.d[0] = *(const u64*)(vp1); V1.d[1] = *(const u64*)(vp1 + 64); vp1 += 128;        \
    V2.d[0] = *(const u64*)(vp2); V2.d[1] = *(const u64*)(vp2 + 64); vp2 += 128;        \
    V3.d[0] = *(const u64*)(vp3); V3.d[1] = *(const u64*)(vp3 + 64); vp3 += 128;

#define QK_PHASE(DGE, DGO, HO)                                                          \
    {                                                                                   \
        const u16* Kb = KW[cur][w];                                                     \
        const bf16x8 kE0 = *(const bf16x8*)(Kb + l15 * 64 + (quad ^ swz) * 8);          \
        const bf16x8 kE1 = *(const bf16x8*)(Kb + l15 * 64 + ((4 ^ quad) ^ swz) * 8);    \
        const bf16x8 kO0 = *(const bf16x8*)(Kb + (16 + l15) * 64 + (quad ^ swz) * 8);   \
        const bf16x8 kO1 = *(const bf16x8*)(Kb + (16 + l15) * 64 + ((4 ^ quad) ^ swz) * 8); \
        __builtin_amdgcn_s_setprio(1);                                                  \
        _Pragma("unroll")                                                               \
        for (int qg = 0; qg < 4; qg++) {                                                \
            const int ql = qg * 16 + l15;                                               \
            f32x4 c = (f32x4){0.f, 0.f, 0.f, 0.f};                                      \
            c = __builtin_amdgcn_mfma_f32_16x16x32_bf16(kE0, qf[qg][0], c, 0, 0, 0);    \
            c = __builtin_amdgcn_mfma_f32_16x16x32_bf16(kE1, qf[qg][1], c, 0, 0, 0);    \
            float p0 = __builtin_amdgcn_exp2f(c[0]);                                    \
            float p1 = __builtin_amdgcn_exp2f(c[1]);                                    \
            float p2 = __builtin_amdgcn_exp2f(c[2]);                                    \
            float p3 = __builtin_amdgcn_exp2f(c[3]);                                    \
            if (DGE) {                                                                  \
                if (keyl + 0 > ql) p0 = 0.f;                                            \
                if (keyl + 1 > ql) p1 = 0.f;                                            \
                if (keyl + 2 > ql) p2 = 0.f;                                            \
                if (keyl + 3 > ql) p3 = 0.f;                                            \
            }                                                                           \
            lp[qg] += (p0 + p1) + (p2 + p3);                                            \
            pu[qg].d[0] = pkbf2f(p0, p1);                                               \
            pu[qg].d[1] = pkbf2f(p2, p3);                                               \
            if (HO) {                                                                   \
                f32x4 cc = (f32x4){0.f, 0.f, 0.f, 0.f};                                 \
                cc = __builtin_amdgcn_mfma_f32_16x16x32_bf16(kO0, qf[qg][0], cc, 0, 0, 0); \
                cc = __builtin_amdgcn_mfma_f32_16x16x32_bf16(kO1, qf[qg][1], cc, 0, 0, 0); \
                float q0 = __builtin_amdgcn_exp2f(cc[0]);                               \
                float q1 = __builtin_amdgcn_exp2f(cc[1]);                               \
                float q2 = __builtin_amdgcn_exp2f(cc[2]);                               \
                float q3 = __builtin_amdgcn_exp2f(cc[3]);                               \
                if (DGO) {                                                              \
                    if (keyl + 0 > ql) q0 = 0.f;                                        \
                    if (keyl + 1 > ql) q1 = 0.f;                                        \
                    if (keyl + 2 > ql) q2 = 0.f;                                        \
                    if (keyl + 3 > ql) q3 = 0.f;                                        \
                }                                                                       \
                lp[qg] += (q0 + q1) + (q2 + q3);                                        \
                pu[qg].d[2] = pkbf2f(q0, q1);                                           \
                pu[qg].d[3] = pkbf2f(q2, q3);                                           \
            } else {                                                                    \
                pu[qg].d[2] = 0u; pu[qg].d[3] = 0u;                                     \
            }                                                                           \
        }                                                                               \
        __builtin_amdgcn_s_setprio(0);                                                  \
    }

#define PV_PHASE(V0, V1, V2, V3)                                                        \
    {                                                                                   \
        __builtin_amdgcn_s_setprio(1);                                                  \
        _Pragma("unroll")                                                               \
        for (int qg = 0; qg < 4; qg++)                                                  \
            o[0][qg] = __builtin_amdgcn_mfma_f32_16x16x32_bf16(V0.v, pu[qg].v, o[0][qg], 0, 0, 0); \
        _Pragma("unroll")                                                               \
        for (int qg = 0; qg < 4; qg++)                                                  \
            o[1][qg] = __builtin_amdgcn_mfma_f32_16x16x32_bf16(V1.v, pu[qg].v, o[1][qg], 0, 0, 0); \
        _Pragma("unroll")                                                               \
        for (int qg = 0; qg < 4; qg++)                                                  \
            o[2][qg] = __builtin_amdgcn_mfma_f32_16x16x32_bf16(V2.v, pu[qg].v, o[2][qg], 0, 0, 0); \
        _Pragma("unroll")                                                               \
        for (int qg = 0; qg < 4; qg++)                                                  \
            o[3][qg] = __builtin_amdgcn_mfma_f32_16x16x32_bf16(V3.v, pu[qg].v, o[3][qg], 0, 0, 0); \
        __builtin_amdgcn_s_setprio(0);                                                  \
    }

    // prologue: K(0) staged (fenced)
    STAGE_K(0, 0);
    MEMFENCE;

    int cur = 0;
    // main loop: all pairs strictly below the diagonal pair (no masks, hasO always)
    for (int kp = 0; kp < np - 1; kp++) {
        STAGE_K(cur ^ 1, kp + 1);                      // group: 4 cp16
        MEMFENCE;
        VU v0, v1, v2, v3;
        LOAD_V(v0, v1, v2, v3);                        // group: 8 u64 reg loads
        MEMFENCE;
        asm volatile("s_waitcnt vmcnt(12)" ::: "memory");  // K(kp) landed; K(kp+1)+V(kp) in flight
        __builtin_amdgcn_sched_barrier(0);
        PU pu[4];
        QK_PHASE(false, false, true);
        asm volatile("s_waitcnt vmcnt(4)" ::: "memory");   // V(kp) landed; K(kp+1) in flight
        __builtin_amdgcn_sched_barrier(0);
        PV_PHASE(v0, v1, v2, v3);
        cur ^= 1;
    }
    // diagonal (last) pair: jq even -> masked even tile only; jq odd -> masked odd tile
    {
        VU v0, v1, v2, v3;
        LOAD_V(v0, v1, v2, v3);
        MEMFENCE;
        asm volatile("s_waitcnt vmcnt(8)" ::: "memory");   // K(last) landed; V(last) in flight
        __builtin_amdgcn_sched_barrier(0);
        const bool dE = !(jq & 1);
        const bool hO = (jq & 1);
        PU pu[4];
        QK_PHASE(dE, true, hO);
        asm volatile("s_waitcnt vmcnt(0)" ::: "memory");   // V(last) landed
        __builtin_amdgcn_sched_barrier(0);
        PV_PHASE(v0, v1, v2, v3);
    }
#undef STAGE_K
#undef LOAD_V
#undef QK_PHASE
#undef PV_PHASE

    // ---- epilogue: cross-wave reduction of l and o, normalize, store ----
    // OR/LR overlay the (dead) KW buffers; all DMA drained (vmcnt(0) above),
    // barrier before overlay.
    float* OR = (float*)&KW[0][0][0];                   // 20.5KB padded o-partials
    float* LR = (float*)((char*)&KW[0][0][0] + 24576);  // 1KB l-partials
#pragma unroll
    for (int qg = 0; qg < 4; qg++) {
        lp[qg] += __shfl_xor(lp[qg], 16);
        lp[qg] += __shfl_xor(lp[qg], 32);
    }
    __syncthreads();                       // all waves done with their regions
    if (lane < 16) {
#pragma unroll
        for (int qg = 0; qg < 4; qg++) LR[(w * 4 + qg) * 16 + lane] = lp[qg];
    }
    const int qrow = tid >> 2;               // this thread reduces (qrow, 4 dims)
    const int qgr = qrow >> 4, lq = qrow & 15;
    const int dpart = (tid & 3) * 4;
    __syncthreads();
    const float lsum = LR[qgr * 16 + lq] + LR[(4 + qgr) * 16 + lq] +
                       LR[(8 + qgr) * 16 + lq] + LR[(12 + qgr) * 16 + lq];
    const float inv = 1.f / lsum;
#pragma unroll
    for (int dg = 0; dg < 4; dg++) {
        if (dg) __syncthreads();             // prev pass reads done before overwrite
#pragma unroll
        for (int qg = 0; qg < 4; qg++)
            *(f32x4*)&OR[((w * 4 + qg) * 16 + l15) * 20 + quad * 4] = o[dg][qg];
        __syncthreads();
        f32x4 s = (f32x4){0.f, 0.f, 0.f, 0.f};
#pragma unroll
        for (int sw = 0; sw < 4; sw++)
            s += *(const f32x4*)&OR[((sw * 4 + qgr) * 16 + lq) * 20 + dpart];
        const u32 y0 = pkbf2(s[0] * inv, s[1] * inv);
        const u32 y1 = pkbf2(s[2] * inv, s[3] * inv);
        *(u64*)(Y + (size_t)(qa + qrow) * DMODEL + head * 64 + dg * 16 + dpart) =
            (u64)y0 | ((u64)y1 << 32);
    }
}

extern "C" void kernel_launch(void* const* d_in, const int* in_sizes, int n_in,
                              void* d_out, int out_size, void* d_ws, size_t ws_size,
                              hipStream_t stream) {
    const float* x  = (const float*)d_in[0];
    const float* wq = (const float*)d_in[1];
    const float* wk = (const float*)d_in[2];
    const float* wv = (const float*)d_in[3];
    const float* wo = (const float*)d_in[4];
    float* out = (float*)d_out;

    u16* qh  = (u16*)d_ws;                            // [0,8) MB
    u16* kh  = qh + (size_t)S_LEN * DMODEL;           // [8,16)
    u16* vt  = kh + (size_t)S_LEN * DMODEL;           // [16,24)
    u16* xb  = vt + (size_t)S_LEN * DMODEL;           // [24,32) x bf16, later y
    u16* y   = xb;                                    // alias after QKV proj
    u16* wb3 = xb + (size_t)S_LEN * DMODEL;           // [32,38) [wq;wk;wv]
    u16* wob = wb3 + (size_t)3 * DMODEL * DMODEL;     // [38,40) wo bf16

    const dim3 blk(256);

    cvt_all<<<4096, blk, 0, stream>>>(x, wq, wk, wv, wo, xb, wb3, wob);
    gemm_qkv<<<dim3(3 * DMODEL / 128, S_LEN / 128), blk, 0, stream>>>(xb, wb3, qh, kh, vt);
    attn<<<1024, blk, 0, stream>>>(qh, kh, vt, y);
    gemm_out<<<512, blk, 0, stream>>>(y, wob, out);
}

// Round 15
// 250.637 us; speedup vs baseline: 1.6871x; 1.6871x over previous
//
#include <hip/hip_runtime.h>

#define S_LEN 4096
#define DMODEL 1024
#define NHEADS 16

typedef __attribute__((ext_vector_type(8))) short bf16x8;
typedef __attribute__((ext_vector_type(4))) float f32x4;
typedef unsigned short u16;
typedef unsigned int u32;
typedef unsigned long long u64;

// IR+MIR memory fence: pins VMEM issue order at group granularity.
#define MEMFENCE asm volatile("" ::: "memory")

__device__ inline u16 f2bf(float f) {
    union { float f; u32 u; } v; v.f = f;
    u32 r = v.u + 0x7fffu + ((v.u >> 16) & 1u);
    return (u16)(r >> 16);
}

// exact RNE pack (epilogues)
__device__ inline u32 pkbf2(float a, float b) {
    union { float f; u32 u; } ua, ub; ua.f = a; ub.f = b;
    const u32 ra = ua.u + 0x7fffu + ((ua.u >> 16) & 1u);
    const u32 rb = ub.u + 0x7fffu + ((ub.u >> 16) & 1u);
    return __builtin_amdgcn_perm(rb, ra, 0x07060302u);
}

// fast pack: round-half-up (3 VALU ops). Differs from RNE only at exact ties.
// NOTE: v_cvt_pk_bf16_f32 inline-asm failed correctness twice (rounds 7,9);
// its operand->half mapping on gfx950 does not match lo=a/hi=b. Keep pkbf2f.
__device__ inline u32 pkbf2f(float a, float b) {
    union { float f; u32 u; } ua, ub; ua.f = a; ub.f = b;
    const u32 ra = ua.u + 0x8000u;
    const u32 rb = ub.u + 0x8000u;
    return __builtin_amdgcn_perm(rb, ra, 0x07060302u);
}

// async 16B global->LDS DMA. LDS dst = wave-uniform base + lane*16 at all sites.
__device__ inline void cp16(const void* g, void* l) {
    __builtin_amdgcn_global_load_lds(
        (const __attribute__((address_space(1))) unsigned int*)g,
        (__attribute__((address_space(3))) unsigned int*)l, 16, 0, 0);
}

// One launch converts x (4M), wq/wk/wv (-> w3 contiguous), wo (-> wob). 4096 blocks.
__global__ __launch_bounds__(256) void cvt_all(const float* __restrict__ x,
                                               const float* __restrict__ wq,
                                               const float* __restrict__ wk,
                                               const float* __restrict__ wv,
                                               const float* __restrict__ wo,
                                               u16* __restrict__ xb,
                                               u16* __restrict__ w3,
                                               u16* __restrict__ wob) {
    const int b = blockIdx.x;
    const float* s; u16* d; int off;
    const int NW = DMODEL * DMODEL;  // 1M
    if (b < 2048)      { s = x;  d = xb;          off = b * 2048; }
    else if (b < 2560) { s = wq; d = w3;          off = (b - 2048) * 2048; }
    else if (b < 3072) { s = wk; d = w3 + NW;     off = (b - 2560) * 2048; }
    else if (b < 3584) { s = wv; d = w3 + 2 * NW; off = (b - 3072) * 2048; }
    else               { s = wo; d = wob;         off = (b - 3584) * 2048; }
    const int i = off + threadIdx.x * 8;
    const float4 a = *(const float4*)(s + i);
    const float4 c = *(const float4*)(s + i + 4);
    u16 t[8];
    t[0] = f2bf(a.x); t[1] = f2bf(a.y); t[2] = f2bf(a.z); t[3] = f2bf(a.w);
    t[4] = f2bf(c.x); t[5] = f2bf(c.y); t[6] = f2bf(c.z); t[7] = f2bf(c.w);
    *(bf16x8*)(d + i) = *(const bf16x8*)t;
}

// Fused QKV projection: C = x(4096x1024) * W3^T (W3 = [wq;wk;wv] 3072x1024).
// Triple-buffered counted-vmcnt pipeline; coalesced scalar Q/K stores,
// u64 V^T stores (round-13, verified).
// Q pre-scaled by 1/8*log2e. Q,K -> [h][m][c]; V -> [h][c][m].
__global__ __launch_bounds__(256) void gemm_qkv(const u16* __restrict__ A,
                                                const u16* __restrict__ B3,
                                                u16* __restrict__ Qo,
                                                u16* __restrict__ Ko,
                                                u16* __restrict__ Vo) {
    __shared__ __align__(16) u16 As[3][128 * 32];   // 24KB
    __shared__ __align__(16) u16 Bs[3][128 * 32];   // 24KB
    const int tid = threadIdx.x, lane = tid & 63, wave = tid >> 6;
    const int wm = (wave >> 1) * 64, wn = (wave & 1) * 64;
    const int m0 = blockIdx.y * 128, n0 = blockIdx.x * 128;
    const int l15 = lane & 15, quad = lane >> 4;

    f32x4 acc[4][4];
#pragma unroll
    for (int i = 0; i < 4; i++)
#pragma unroll
        for (int j = 0; j < 4; j++) acc[i][j] = (f32x4){0.f, 0.f, 0.f, 0.f};

    const int r0 = tid >> 2, c0 = (tid & 3) * 8;

// one K-step stage (16KB = 4 cp16/thread) into buffer `buf`
#define STAGE_QKV(buf, kkb)                                                        \
    {                                                                              \
        cp16(A + (size_t)(m0 + r0) * 1024 + (kkb) + c0,       As[buf] + r0 * 32 + c0); \
        cp16(A + (size_t)(m0 + r0 + 64) * 1024 + (kkb) + c0,  As[buf] + (r0 + 64) * 32 + c0); \
        cp16(B3 + (size_t)(n0 + r0) * 1024 + (kkb) + c0,      Bs[buf] + r0 * 32 + c0); \
        cp16(B3 + (size_t)(n0 + r0 + 64) * 1024 + (kkb) + c0, Bs[buf] + (r0 + 64) * 32 + c0); \
    }

#define COMPUTE_QKV(cur)                                                           \
    {                                                                              \
        bf16x8 af[4], bfr[4];                                                      \
        _Pragma("unroll")                                                          \
        for (int i = 0; i < 4; i++)                                                \
            af[i] = *(const bf16x8*)(As[cur] + (wm + i * 16 + l15) * 32 + quad * 8); \
        _Pragma("unroll")                                                          \
        for (int j = 0; j < 4; j++)                                                \
            bfr[j] = *(const bf16x8*)(Bs[cur] + (wn + j * 16 + l15) * 32 + quad * 8); \
        _Pragma("unroll")                                                          \
        for (int i = 0; i < 4; i++)                                                \
            _Pragma("unroll")                                                      \
            for (int j = 0; j < 4; j++)                                            \
                acc[i][j] = __builtin_amdgcn_mfma_f32_16x16x32_bf16(af[i], bfr[j], acc[i][j], 0, 0, 0); \
    }

    // prologue: 2 stages in flight (8 cp16/thread)
    STAGE_QKV(0, 0);
    MEMFENCE;
    STAGE_QKV(1, 32);
    MEMFENCE;

    // main loop: 31 steps with counted wait (stage k+1 stays in flight)
    for (int ks = 0; ks < 31; ks++) {
        asm volatile("s_waitcnt vmcnt(4)" ::: "memory");  // my stage(ks) landed
        __builtin_amdgcn_s_barrier();                     // everyone's stage(ks) landed
        __builtin_amdgcn_sched_barrier(0);
        if (ks < 30) {
            STAGE_QKV((ks + 2) % 3, (ks + 2) * 32);       // 2 steps of latency cover
            MEMFENCE;
        }
        COMPUTE_QKV(ks % 3);
    }
    // tail step 31: drain and compute
    asm volatile("s_waitcnt vmcnt(0)" ::: "memory");
    __builtin_amdgcn_s_barrier();
    __builtin_amdgcn_sched_barrier(0);
    COMPUTE_QKV(1);                                       // 31 % 3 == 1
#undef STAGE_QKV
#undef COMPUTE_QKV

    const int which = n0 >> 10;
    const int n0r = n0 & 1023;
    u16* dst = (which == 0) ? Qo : (which == 1) ? Ko : Vo;
    if (which < 2) {
        // coalesced scalar stores: quarter-wave (l15) = 16 consecutive cols (32B)
        const float sc = (which == 0) ? 0.125f * 1.4426950408889634f : 1.0f;
#pragma unroll
        for (int i = 0; i < 4; i++)
#pragma unroll
            for (int j = 0; j < 4; j++) {
                const int col = n0r + wn + j * 16 + l15;
                const int h = col >> 6, c = col & 63;
#pragma unroll
                for (int r = 0; r < 4; r++) {
                    const int row = m0 + wm + i * 16 + quad * 4 + r;
                    dst[(size_t)h * S_LEN * 64 + (size_t)row * 64 + c] = f2bf(acc[i][j][r] * sc);
                }
            }
    } else {
        // V^T: r=0..3 are 4 consecutive u16 in memory -> u64 store (verified r11)
#pragma unroll
        for (int i = 0; i < 4; i++) {
            const int row0 = m0 + wm + i * 16 + quad * 4;
#pragma unroll
            for (int j = 0; j < 4; j++) {
                const int col = n0r + wn + j * 16 + l15;
                const int h = col >> 6, c = col & 63;
                const u32 y0 = pkbf2(acc[i][j][0], acc[i][j][1]);
                const u32 y1 = pkbf2(acc[i][j][2], acc[i][j][3]);
                *(u64*)(dst + (size_t)h * S_LEN * 64 + (size_t)c * S_LEN + row0) =
                    (u64)y0 | ((u64)y1 << 32);
            }
        }
    }
}

// Output projection: C(fp32 [4096][1024]) = y(bf16) * wo^T. Split-M:
// 64x128 tiles, grid 512 (2/CU), BK=64, dbuf single-barrier, swizzled LDS,
// plain coalesced fp32 stores (round-8 form, verified).
__global__ __launch_bounds__(256) void gemm_out(const u16* __restrict__ A,
                                                const u16* __restrict__ B,
                                                float* __restrict__ C) {
    __shared__ __align__(16) u16 As[2][64 * 64];    // swizzled [row][col]
    __shared__ __align__(16) u16 Bs[2][128 * 64];   // swizzled [row][col]
    const int tid = threadIdx.x, lane = tid & 63, wave = tid >> 6;
    const int wm = (wave >> 1) * 32, wn = (wave & 1) * 64;
    const int bx = blockIdx.x;
    const int n0 = (bx & 7) * 128, m0 = (bx >> 3) * 64;
    const int l15 = lane & 15, quad = lane >> 4;
    const int swz = l15 & 7;

    f32x4 acc[2][4];
#pragma unroll
    for (int i = 0; i < 2; i++)
#pragma unroll
        for (int j = 0; j < 4; j++) acc[i][j] = (f32x4){0.f, 0.f, 0.f, 0.f};

#define STAGE_OUT(buf, kb)                                                              \
    {                                                                                   \
        _Pragma("unroll")                                                               \
        for (int q = 0; q < 2; q++) {                                                   \
            const int ch = tid + q * 256;                                               \
            const int ar = ch >> 3, ac = ((ch & 7) ^ (ar & 7)) * 8;                     \
            cp16(A + (size_t)(m0 + ar) * 1024 + (kb) + ac, As[buf] + ch * 8);           \
        }                                                                               \
        _Pragma("unroll")                                                               \
        for (int q = 0; q < 4; q++) {                                                   \
            const int ch = tid + q * 256;                                               \
            const int br = ch >> 3, bc = ((ch & 7) ^ (br & 7)) * 8;                     \
            cp16(B + (size_t)(n0 + br) * 1024 + (kb) + bc, Bs[buf] + ch * 8);           \
        }                                                                               \
    }

    STAGE_OUT(0, 0);
    int cur = 0;
    for (int kk = 0; kk < 1024; kk += 64) {
        __syncthreads();  // drains vmcnt(0): buf[cur] ready, buf[cur^1] reads done
        if (kk + 64 < 1024) STAGE_OUT(cur ^ 1, kk + 64);
#pragma unroll
        for (int h = 0; h < 2; h++) {
            const int cc = (h * 4 + quad) ^ swz;
            bf16x8 af[2], bfr[4];
#pragma unroll
            for (int i = 0; i < 2; i++)
                af[i] = *(const bf16x8*)(As[cur] + (wm + i * 16 + l15) * 64 + cc * 8);
#pragma unroll
            for (int j = 0; j < 4; j++)
                bfr[j] = *(const bf16x8*)(Bs[cur] + (wn + j * 16 + l15) * 64 + cc * 8);
#pragma unroll
            for (int i = 0; i < 2; i++)
#pragma unroll
                for (int j = 0; j < 4; j++)
                    acc[i][j] = __builtin_amdgcn_mfma_f32_16x16x32_bf16(af[i], bfr[j], acc[i][j], 0, 0, 0);
        }
        cur ^= 1;
    }
#undef STAGE_OUT

#pragma unroll
    for (int i = 0; i < 2; i++)
#pragma unroll
        for (int j = 0; j < 4; j++)
#pragma unroll
            for (int r = 0; r < 4; r++) {
                const int row = m0 + wm + i * 16 + quad * 4 + r;
                const int col = n0 + wn + j * 16 + l15;
                C[(size_t)row * 1024 + col] = acc[i][j][r];
            }
}

// Flash attention, causal — round-15: V DIRECT-TO-REGISTER at (256,3).
// Round-14 post-mortem: __launch_bounds__(256,4) made the allocator target
// the 64-VGPR bucket -> massive scratch spill (FETCH 387MB). The V-direct
// design itself is sound (round-2's kernel used the same V register pattern
// at (256,3), 80 VGPR, no spill). Single delta from round 14: bound 4 -> 3.
// Effective delta vs verified round-13: V loads straight from L2 into
// registers at iteration top (8 x u64/pair), consumed in PV a full
// QK+softmax (~400cy) later — removes 4 cp16 + 8 ds_read + V addr math per
// pair at unchanged occupancy. K keeps the LDS pair-dbuf.
// vmcnt arithmetic (in-order VMEM retirement): steady iter kp outstanding
// after issue = K(kp)4 + K(kp+1)4 + V(kp)8; QK needs K(kp): vmcnt(12);
// PV needs V(kp): vmcnt(4). First iter: +Qf8 oldest -> vmcnt(12) retires
// Qf8+K(0)4 exactly. Diagonal: vmcnt(8) then vmcnt(0). MEMFENCE pins all
// load groups; setprio(1) wraps MFMA clusters (T5, verified round-13).
// Q (pre-scaled by 1/8*log2e), K: [H][S][64] bf16. Vt: [H][64][S] bf16.
// Y: [S][DMODEL] bf16.
__global__ __launch_bounds__(256, 3) void attn(const u16* __restrict__ Q,
                                               const u16* __restrict__ Kh,
                                               const u16* __restrict__ Vt,
                                               u16* __restrict__ Y) {
    __shared__ __align__(16) u16 KW[2][4][2048];  // 32KB: per-wave K pair dbuf
    const int b = blockIdx.x;
    const int head = b & 15;                      // head pinned to XCD (b%8)
    const int jq = 63 - (b >> 4);                 // longest q-tile first
    const int nkt = jq + 1;                       // 64-key tiles this block needs
    const int np = (nkt + 1) >> 1;                // key-tile PAIRS (incl. odd tail)
    const int qa = jq * 64;
    const int tid = threadIdx.x, lane = tid & 63, w = tid >> 6;
    const int l15 = lane & 15, quad = lane >> 4;
    const int swz = l15 & 7;

    const u16* Qp = Q + (size_t)head * S_LEN * 64;
    const u16* Kp = Kh + (size_t)head * S_LEN * 64;
    const u16* Vp = Vt + (size_t)head * 64 * S_LEN;

    // Q fragments: all 64 q-rows in registers (B-operand: n=l15 row, k=quad*8 dims)
    bf16x8 qf[4][2];
#pragma unroll
    for (int qg = 0; qg < 4; qg++)
#pragma unroll
        for (int h = 0; h < 2; h++)
            qf[qg][h] = *(const bf16x8*)(Qp + (size_t)(qa + qg * 16 + l15) * 64 + h * 32 + quad * 8);
    MEMFENCE;   // qf loads are the oldest VMEM group

    f32x4 o[4][4];   // o[dg][qg]: dim = dg*16+quad*4+r, qrow = qg*16+l15
#pragma unroll
    for (int dg = 0; dg < 4; dg++)
#pragma unroll
        for (int qg = 0; qg < 4; qg++) o[dg][qg] = (f32x4){0.f, 0.f, 0.f, 0.f};
    float lp[4] = {0.f, 0.f, 0.f, 0.f};

    const int keyl = w * 16 + quad * 4;           // key-in-tile of this lane's 4 scores

    // walking V pointers (u16 units): wave's 16-key stripe, 4 dim-groups.
    // vf.d[0] = even-tile keys quad*4.., vf.d[1] = odd-tile (+64).
    const u16* vp0 = Vp + (size_t)l15 * S_LEN + w * 16 + quad * 4;
    const u16* vp1 = vp0 + (size_t)16 * S_LEN;
    const u16* vp2 = vp0 + (size_t)32 * S_LEN;
    const u16* vp3 = vp0 + (size_t)48 * S_LEN;

    union PU { u32 d[4]; bf16x8 v; };
    union VU { u64 d[2]; bf16x8 v; };

// Per-wave K stage: one PAIR stripe (rows 0-15 even tile, 16-31 odd), 4 cp16.
// LDS linear (base + lane*16); swizzle via global source: logchunk = (lane&7)^(lane>>3).
#define STAGE_K(buf, kp2)                                                               \
    {                                                                                   \
        _Pragma("unroll")                                                               \
        for (int i = 0; i < 4; i++) {                                                   \
            const int gk = (kp2) * 128 + w * 16 + (i & 1) * 8 + (lane >> 3) + (i >> 1) * 64; \
            const int lc = (lane & 7) ^ (lane >> 3);                                    \
            cp16(Kp + (size_t)gk * 64 + lc * 8, KW[buf][w] + i * 512 + lane * 8);       \
        }                                                                               \
    }

// V direct loads for one pair into named VU set (8 x u64), pointers walk.
#define LOAD_V(V0, V1, V2, V3)                                                          \
    V0.d[0] = *(const u64*)(vp0); V0.d[1] = *(const u64*)(vp0 + 64); vp0 += 128;        \
    V1.d[0] = *(const u64*)(vp1); V1.d[1] = *(const u64*)(vp1 + 64); vp1 += 128;        \
    V2.d[0] = *(const u64*)(vp2); V2.d[1] = *(const u64*)(vp2 + 64); vp2 += 128;        \
    V3.d[0] = *(const u64*)(vp3); V3.d[1] = *(const u64*)(vp3 + 64); vp3 += 128;

#define QK_PHASE(DGE, DGO, HO)                                                          \
    {                                                                                   \
        const u16* Kb = KW[cur][w];                                                     \
        const bf16x8 kE0 = *(const bf16x8*)(Kb + l15 * 64 + (quad ^ swz) * 8);          \
        const bf16x8 kE1 = *(const bf16x8*)(Kb + l15 * 64 + ((4 ^ quad) ^ swz) * 8);    \
        const bf16x8 kO0 = *(const bf16x8*)(Kb + (16 + l15) * 64 + (quad ^ swz) * 8);   \
        const bf16x8 kO1 = *(const bf16x8*)(Kb + (16 + l15) * 64 + ((4 ^ quad) ^ swz) * 8); \
        __builtin_amdgcn_s_setprio(1);                                                  \
        _Pragma("unroll")                                                               \
        for (int qg = 0; qg < 4; qg++) {                                                \
            const int ql = qg * 16 + l15;                                               \
            f32x4 c = (f32x4){0.f, 0.f, 0.f, 0.f};                                      \
            c = __builtin_amdgcn_mfma_f32_16x16x32_bf16(kE0, qf[qg][0], c, 0, 0, 0);    \
            c = __builtin_amdgcn_mfma_f32_16x16x32_bf16(kE1, qf[qg][1], c, 0, 0, 0);    \
            float p0 = __builtin_amdgcn_exp2f(c[0]);                                    \
            float p1 = __builtin_amdgcn_exp2f(c[1]);                                    \
            float p2 = __builtin_amdgcn_exp2f(c[2]);                                    \
            float p3 = __builtin_amdgcn_exp2f(c[3]);                                    \
            if (DGE) {                                                                  \
                if (keyl + 0 > ql) p0 = 0.f;                                            \
                if (keyl + 1 > ql) p1 = 0.f;                                            \
                if (keyl + 2 > ql) p2 = 0.f;                                            \
                if (keyl + 3 > ql) p3 = 0.f;                                            \
            }                                                                           \
            lp[qg] += (p0 + p1) + (p2 + p3);                                            \
            pu[qg].d[0] = pkbf2f(p0, p1);                                               \
            pu[qg].d[1] = pkbf2f(p2, p3);                                               \
            if (HO) {                                                                   \
                f32x4 cc = (f32x4){0.f, 0.f, 0.f, 0.f};                                 \
                cc = __builtin_amdgcn_mfma_f32_16x16x32_bf16(kO0, qf[qg][0], cc, 0, 0, 0); \
                cc = __builtin_amdgcn_mfma_f32_16x16x32_bf16(kO1, qf[qg][1], cc, 0, 0, 0); \
                float q0 = __builtin_amdgcn_exp2f(cc[0]);                               \
                float q1 = __builtin_amdgcn_exp2f(cc[1]);                               \
                float q2 = __builtin_amdgcn_exp2f(cc[2]);                               \
                float q3 = __builtin_amdgcn_exp2f(cc[3]);                               \
                if (DGO) {                                                              \
                    if (keyl + 0 > ql) q0 = 0.f;                                        \
                    if (keyl + 1 > ql) q1 = 0.f;                                        \
                    if (keyl + 2 > ql) q2 = 0.f;                                        \
                    if (keyl + 3 > ql) q3 = 0.f;                                        \
                }                                                                       \
                lp[qg] += (q0 + q1) + (q2 + q3);                                        \
                pu[qg].d[2] = pkbf2f(q0, q1);                                           \
                pu[qg].d[3] = pkbf2f(q2, q3);                                           \
            } else {                                                                    \
                pu[qg].d[2] = 0u; pu[qg].d[3] = 0u;                                     \
            }                                                                           \
        }                                                                               \
        __builtin_amdgcn_s_setprio(0);                                                  \
    }

#define PV_PHASE(V0, V1, V2, V3)                                                        \
    {                                                                                   \
        __builtin_amdgcn_s_setprio(1);                                                  \
        _Pragma("unroll")                                                               \
        for (int qg = 0; qg < 4; qg++)                                                  \
            o[0][qg] = __builtin_amdgcn_mfma_f32_16x16x32_bf16(V0.v, pu[qg].v, o[0][qg], 0, 0, 0); \
        _Pragma("unroll")                                                               \
        for (int qg = 0; qg < 4; qg++)                                                  \
            o[1][qg] = __builtin_amdgcn_mfma_f32_16x16x32_bf16(V1.v, pu[qg].v, o[1][qg], 0, 0, 0); \
        _Pragma("unroll")                                                               \
        for (int qg = 0; qg < 4; qg++)                                                  \
            o[2][qg] = __builtin_amdgcn_mfma_f32_16x16x32_bf16(V2.v, pu[qg].v, o[2][qg], 0, 0, 0); \
        _Pragma("unroll")                                                               \
        for (int qg = 0; qg < 4; qg++)                                                  \
            o[3][qg] = __builtin_amdgcn_mfma_f32_16x16x32_bf16(V3.v, pu[qg].v, o[3][qg], 0, 0, 0); \
        __builtin_amdgcn_s_setprio(0);                                                  \
    }

    // prologue: K(0) staged (fenced)
    STAGE_K(0, 0);
    MEMFENCE;

    int cur = 0;
    // main loop: all pairs strictly below the diagonal pair (no masks, hasO always)
    for (int kp = 0; kp < np - 1; kp++) {
        STAGE_K(cur ^ 1, kp + 1);                      // group: 4 cp16
        MEMFENCE;
        VU v0, v1, v2, v3;
        LOAD_V(v0, v1, v2, v3);                        // group: 8 u64 reg loads
        MEMFENCE;
        asm volatile("s_waitcnt vmcnt(12)" ::: "memory");  // K(kp) landed; K(kp+1)+V(kp) in flight
        __builtin_amdgcn_sched_barrier(0);
        PU pu[4];
        QK_PHASE(false, false, true);
        asm volatile("s_waitcnt vmcnt(4)" ::: "memory");   // V(kp) landed; K(kp+1) in flight
        __builtin_amdgcn_sched_barrier(0);
        PV_PHASE(v0, v1, v2, v3);
        cur ^= 1;
    }
    // diagonal (last) pair: jq even -> masked even tile only; jq odd -> masked odd tile
    {
        VU v0, v1, v2, v3;
        LOAD_V(v0, v1, v2, v3);
        MEMFENCE;
        asm volatile("s_waitcnt vmcnt(8)" ::: "memory");   // K(last) landed; V(last) in flight
        __builtin_amdgcn_sched_barrier(0);
        const bool dE = !(jq & 1);
        const bool hO = (jq & 1);
        PU pu[4];
        QK_PHASE(dE, true, hO);
        asm volatile("s_waitcnt vmcnt(0)" ::: "memory");   // V(last) landed
        __builtin_amdgcn_sched_barrier(0);
        PV_PHASE(v0, v1, v2, v3);
    }
#undef STAGE_K
#undef LOAD_V
#undef QK_PHASE
#undef PV_PHASE

    // ---- epilogue: cross-wave reduction of l and o, normalize, store ----
    // OR/LR overlay the (dead) KW buffers; all DMA drained (vmcnt(0) above),
    // barrier before overlay.
    float* OR = (float*)&KW[0][0][0];                   // 20.5KB padded o-partials
    float* LR = (float*)((char*)&KW[0][0][0] + 24576);  // 1KB l-partials
#pragma unroll
    for (int qg = 0; qg < 4; qg++) {
        lp[qg] += __shfl_xor(lp[qg], 16);
        lp[qg] += __shfl_xor(lp[qg], 32);
    }
    __syncthreads();                       // all waves done with their regions
    if (lane < 16) {
#pragma unroll
        for (int qg = 0; qg < 4; qg++) LR[(w * 4 + qg) * 16 + lane] = lp[qg];
    }
    const int qrow = tid >> 2;               // this thread reduces (qrow, 4 dims)
    const int qgr = qrow >> 4, lq = qrow & 15;
    const int dpart = (tid & 3) * 4;
    __syncthreads();
    const float lsum = LR[qgr * 16 + lq] + LR[(4 + qgr) * 16 + lq] +
                       LR[(8 + qgr) * 16 + lq] + LR[(12 + qgr) * 16 + lq];
    const float inv = 1.f / lsum;
#pragma unroll
    for (int dg = 0; dg < 4; dg++) {
        if (dg) __syncthreads();             // prev pass reads done before overwrite
#pragma unroll
        for (int qg = 0; qg < 4; qg++)
            *(f32x4*)&OR[((w * 4 + qg) * 16 + l15) * 20 + quad * 4] = o[dg][qg];
        __syncthreads();
        f32x4 s = (f32x4){0.f, 0.f, 0.f, 0.f};
#pragma unroll
        for (int sw = 0; sw < 4; sw++)
            s += *(const f32x4*)&OR[((sw * 4 + qgr) * 16 + lq) * 20 + dpart];
        const u32 y0 = pkbf2(s[0] * inv, s[1] * inv);
        const u32 y1 = pkbf2(s[2] * inv, s[3] * inv);
        *(u64*)(Y + (size_t)(qa + qrow) * DMODEL + head * 64 + dg * 16 + dpart) =
            (u64)y0 | ((u64)y1 << 32);
    }
}

extern "C" void kernel_launch(void* const* d_in, const int* in_sizes, int n_in,
                              void* d_out, int out_size, void* d_ws, size_t ws_size,
                              hipStream_t stream) {
    const float* x  = (const float*)d_in[0];
    const float* wq = (const float*)d_in[1];
    const float* wk = (const float*)d_in[2];
    const float* wv = (const float*)d_in[3];
    const float* wo = (const float*)d_in[4];
    float* out = (float*)d_out;

    u16* qh  = (u16*)d_ws;                            // [0,8) MB
    u16* kh  = qh + (size_t)S_LEN * DMODEL;           // [8,16)
    u16* vt  = kh + (size_t)S_LEN * DMODEL;           // [16,24)
    u16* xb  = vt + (size_t)S_LEN * DMODEL;           // [24,32) x bf16, later y
    u16* y   = xb;                                    // alias after QKV proj
    u16* wb3 = xb + (size_t)S_LEN * DMODEL;           // [32,38) [wq;wk;wv]
    u16* wob = wb3 + (size_t)3 * DMODEL * DMODEL;     // [38,40) wo bf16

    const dim3 blk(256);

    cvt_all<<<4096, blk, 0, stream>>>(x, wq, wk, wv, wo, xb, wb3, wob);
    gemm_qkv<<<dim3(3 * DMODEL / 128, S_LEN / 128), blk, 0, stream>>>(xb, wb3, qh, kh, vt);
    attn<<<1024, blk, 0, stream>>>(qh, kh, vt, y);
    gemm_out<<<512, blk, 0, stream>>>(y, wob, out);
}

// Round 16
// 203.699 us; speedup vs baseline: 2.0758x; 1.2304x over previous
//
#include <hip/hip_runtime.h>

#define S_LEN 4096
#define DMODEL 1024
#define NHEADS 16

typedef __attribute__((ext_vector_type(8))) short bf16x8;
typedef __attribute__((ext_vector_type(4))) float f32x4;
typedef unsigned short u16;
typedef unsigned int u32;
typedef unsigned long long u64;

// IR+MIR memory fence: pins global_load_lds issue order at group granularity.
#define MEMFENCE asm volatile("" ::: "memory")

__device__ inline u16 f2bf(float f) {
    union { float f; u32 u; } v; v.f = f;
    u32 r = v.u + 0x7fffu + ((v.u >> 16) & 1u);
    return (u16)(r >> 16);
}

// exact RNE pack (epilogues)
__device__ inline u32 pkbf2(float a, float b) {
    union { float f; u32 u; } ua, ub; ua.f = a; ub.f = b;
    const u32 ra = ua.u + 0x7fffu + ((ua.u >> 16) & 1u);
    const u32 rb = ub.u + 0x7fffu + ((ub.u >> 16) & 1u);
    return __builtin_amdgcn_perm(rb, ra, 0x07060302u);
}

// fast pack: round-half-up (3 VALU ops). Differs from RNE only at exact ties.
// NOTE: v_cvt_pk_bf16_f32 inline-asm failed correctness twice (rounds 7,9);
// its operand->half mapping on gfx950 does not match lo=a/hi=b. Keep pkbf2f.
__device__ inline u32 pkbf2f(float a, float b) {
    union { float f; u32 u; } ua, ub; ua.f = a; ub.f = b;
    const u32 ra = ua.u + 0x8000u;
    const u32 rb = ub.u + 0x8000u;
    return __builtin_amdgcn_perm(rb, ra, 0x07060302u);
}

// async 16B global->LDS DMA. LDS dst = wave-uniform base + lane*16 at all sites.
__device__ inline void cp16(const void* g, void* l) {
    __builtin_amdgcn_global_load_lds(
        (const __attribute__((address_space(1))) unsigned int*)g,
        (__attribute__((address_space(3))) unsigned int*)l, 16, 0, 0);
}

// One launch converts x (4M), wq/wk/wv (-> w3 contiguous), wo (-> wob). 4096 blocks.
__global__ __launch_bounds__(256) void cvt_all(const float* __restrict__ x,
                                               const float* __restrict__ wq,
                                               const float* __restrict__ wk,
                                               const float* __restrict__ wv,
                                               const float* __restrict__ wo,
                                               u16* __restrict__ xb,
                                               u16* __restrict__ w3,
                                               u16* __restrict__ wob) {
    const int b = blockIdx.x;
    const float* s; u16* d; int off;
    const int NW = DMODEL * DMODEL;  // 1M
    if (b < 2048)      { s = x;  d = xb;          off = b * 2048; }
    else if (b < 2560) { s = wq; d = w3;          off = (b - 2048) * 2048; }
    else if (b < 3072) { s = wk; d = w3 + NW;     off = (b - 2560) * 2048; }
    else if (b < 3584) { s = wv; d = w3 + 2 * NW; off = (b - 3072) * 2048; }
    else               { s = wo; d = wob;         off = (b - 3584) * 2048; }
    const int i = off + threadIdx.x * 8;
    const float4 a = *(const float4*)(s + i);
    const float4 c = *(const float4*)(s + i + 4);
    u16 t[8];
    t[0] = f2bf(a.x); t[1] = f2bf(a.y); t[2] = f2bf(a.z); t[3] = f2bf(a.w);
    t[4] = f2bf(c.x); t[5] = f2bf(c.y); t[6] = f2bf(c.z); t[7] = f2bf(c.w);
    *(bf16x8*)(d + i) = *(const bf16x8*)t;
}

// Fused QKV projection: C = x(4096x1024) * W3^T (W3 = [wq;wk;wv] 3072x1024).
// Triple-buffered counted-vmcnt pipeline; coalesced scalar Q/K stores,
// u64 V^T stores (round-13, verified: < 59.5us).
// Q pre-scaled by 1/8*log2e. Q,K -> [h][m][c]; V -> [h][c][m].
__global__ __launch_bounds__(256) void gemm_qkv(const u16* __restrict__ A,
                                                const u16* __restrict__ B3,
                                                u16* __restrict__ Qo,
                                                u16* __restrict__ Ko,
                                                u16* __restrict__ Vo) {
    __shared__ __align__(16) u16 As[3][128 * 32];   // 24KB
    __shared__ __align__(16) u16 Bs[3][128 * 32];   // 24KB
    const int tid = threadIdx.x, lane = tid & 63, wave = tid >> 6;
    const int wm = (wave >> 1) * 64, wn = (wave & 1) * 64;
    const int m0 = blockIdx.y * 128, n0 = blockIdx.x * 128;
    const int l15 = lane & 15, quad = lane >> 4;

    f32x4 acc[4][4];
#pragma unroll
    for (int i = 0; i < 4; i++)
#pragma unroll
        for (int j = 0; j < 4; j++) acc[i][j] = (f32x4){0.f, 0.f, 0.f, 0.f};

    const int r0 = tid >> 2, c0 = (tid & 3) * 8;

// one K-step stage (16KB = 4 cp16/thread) into buffer `buf`
#define STAGE_QKV(buf, kkb)                                                        \
    {                                                                              \
        cp16(A + (size_t)(m0 + r0) * 1024 + (kkb) + c0,       As[buf] + r0 * 32 + c0); \
        cp16(A + (size_t)(m0 + r0 + 64) * 1024 + (kkb) + c0,  As[buf] + (r0 + 64) * 32 + c0); \
        cp16(B3 + (size_t)(n0 + r0) * 1024 + (kkb) + c0,      Bs[buf] + r0 * 32 + c0); \
        cp16(B3 + (size_t)(n0 + r0 + 64) * 1024 + (kkb) + c0, Bs[buf] + (r0 + 64) * 32 + c0); \
    }

#define COMPUTE_QKV(cur)                                                           \
    {                                                                              \
        bf16x8 af[4], bfr[4];                                                      \
        _Pragma("unroll")                                                          \
        for (int i = 0; i < 4; i++)                                                \
            af[i] = *(const bf16x8*)(As[cur] + (wm + i * 16 + l15) * 32 + quad * 8); \
        _Pragma("unroll")                                                          \
        for (int j = 0; j < 4; j++)                                                \
            bfr[j] = *(const bf16x8*)(Bs[cur] + (wn + j * 16 + l15) * 32 + quad * 8); \
        _Pragma("unroll")                                                          \
        for (int i = 0; i < 4; i++)                                                \
            _Pragma("unroll")                                                      \
            for (int j = 0; j < 4; j++)                                            \
                acc[i][j] = __builtin_amdgcn_mfma_f32_16x16x32_bf16(af[i], bfr[j], acc[i][j], 0, 0, 0); \
    }

    // prologue: 2 stages in flight (8 cp16/thread)
    STAGE_QKV(0, 0);
    MEMFENCE;
    STAGE_QKV(1, 32);
    MEMFENCE;

    // main loop: 31 steps with counted wait (stage k+1 stays in flight)
    for (int ks = 0; ks < 31; ks++) {
        asm volatile("s_waitcnt vmcnt(4)" ::: "memory");  // my stage(ks) landed
        __builtin_amdgcn_s_barrier();                     // everyone's stage(ks) landed
        __builtin_amdgcn_sched_barrier(0);
        if (ks < 30) {
            STAGE_QKV((ks + 2) % 3, (ks + 2) * 32);       // 2 steps of latency cover
            MEMFENCE;
        }
        COMPUTE_QKV(ks % 3);
    }
    // tail step 31: drain and compute
    asm volatile("s_waitcnt vmcnt(0)" ::: "memory");
    __builtin_amdgcn_s_barrier();
    __builtin_amdgcn_sched_barrier(0);
    COMPUTE_QKV(1);                                       // 31 % 3 == 1
#undef STAGE_QKV
#undef COMPUTE_QKV

    const int which = n0 >> 10;
    const int n0r = n0 & 1023;
    u16* dst = (which == 0) ? Qo : (which == 1) ? Ko : Vo;
    if (which < 2) {
        // coalesced scalar stores: quarter-wave (l15) = 16 consecutive cols (32B)
        const float sc = (which == 0) ? 0.125f * 1.4426950408889634f : 1.0f;
#pragma unroll
        for (int i = 0; i < 4; i++)
#pragma unroll
            for (int j = 0; j < 4; j++) {
                const int col = n0r + wn + j * 16 + l15;
                const int h = col >> 6, c = col & 63;
#pragma unroll
                for (int r = 0; r < 4; r++) {
                    const int row = m0 + wm + i * 16 + quad * 4 + r;
                    dst[(size_t)h * S_LEN * 64 + (size_t)row * 64 + c] = f2bf(acc[i][j][r] * sc);
                }
            }
    } else {
        // V^T: r=0..3 are 4 consecutive u16 in memory -> u64 store (verified r11)
#pragma unroll
        for (int i = 0; i < 4; i++) {
            const int row0 = m0 + wm + i * 16 + quad * 4;
#pragma unroll
            for (int j = 0; j < 4; j++) {
                const int col = n0r + wn + j * 16 + l15;
                const int h = col >> 6, c = col & 63;
                const u32 y0 = pkbf2(acc[i][j][0], acc[i][j][1]);
                const u32 y1 = pkbf2(acc[i][j][2], acc[i][j][3]);
                *(u64*)(dst + (size_t)h * S_LEN * 64 + (size_t)c * S_LEN + row0) =
                    (u64)y0 | ((u64)y1 << 32);
            }
        }
    }
}

// Output projection: C(fp32 [4096][1024]) = y(bf16) * wo^T. Split-M:
// 64x128 tiles, grid 512 (2/CU), BK=64, dbuf single-barrier, swizzled LDS,
// plain coalesced fp32 stores (round-8 form, verified).
__global__ __launch_bounds__(256) void gemm_out(const u16* __restrict__ A,
                                                const u16* __restrict__ B,
                                                float* __restrict__ C) {
    __shared__ __align__(16) u16 As[2][64 * 64];    // swizzled [row][col]
    __shared__ __align__(16) u16 Bs[2][128 * 64];   // swizzled [row][col]
    const int tid = threadIdx.x, lane = tid & 63, wave = tid >> 6;
    const int wm = (wave >> 1) * 32, wn = (wave & 1) * 64;
    const int bx = blockIdx.x;
    const int n0 = (bx & 7) * 128, m0 = (bx >> 3) * 64;
    const int l15 = lane & 15, quad = lane >> 4;
    const int swz = l15 & 7;

    f32x4 acc[2][4];
#pragma unroll
    for (int i = 0; i < 2; i++)
#pragma unroll
        for (int j = 0; j < 4; j++) acc[i][j] = (f32x4){0.f, 0.f, 0.f, 0.f};

#define STAGE_OUT(buf, kb)                                                              \
    {                                                                                   \
        _Pragma("unroll")                                                               \
        for (int q = 0; q < 2; q++) {                                                   \
            const int ch = tid + q * 256;                                               \
            const int ar = ch >> 3, ac = ((ch & 7) ^ (ar & 7)) * 8;                     \
            cp16(A + (size_t)(m0 + ar) * 1024 + (kb) + ac, As[buf] + ch * 8);           \
        }                                                                               \
        _Pragma("unroll")                                                               \
        for (int q = 0; q < 4; q++) {                                                   \
            const int ch = tid + q * 256;                                               \
            const int br = ch >> 3, bc = ((ch & 7) ^ (br & 7)) * 8;                     \
            cp16(B + (size_t)(n0 + br) * 1024 + (kb) + bc, Bs[buf] + ch * 8);           \
        }                                                                               \
    }

    STAGE_OUT(0, 0);
    int cur = 0;
    for (int kk = 0; kk < 1024; kk += 64) {
        __syncthreads();  // drains vmcnt(0): buf[cur] ready, buf[cur^1] reads done
        if (kk + 64 < 1024) STAGE_OUT(cur ^ 1, kk + 64);
#pragma unroll
        for (int h = 0; h < 2; h++) {
            const int cc = (h * 4 + quad) ^ swz;
            bf16x8 af[2], bfr[4];
#pragma unroll
            for (int i = 0; i < 2; i++)
                af[i] = *(const bf16x8*)(As[cur] + (wm + i * 16 + l15) * 64 + cc * 8);
#pragma unroll
            for (int j = 0; j < 4; j++)
                bfr[j] = *(const bf16x8*)(Bs[cur] + (wn + j * 16 + l15) * 64 + cc * 8);
#pragma unroll
            for (int i = 0; i < 2; i++)
#pragma unroll
                for (int j = 0; j < 4; j++)
                    acc[i][j] = __builtin_amdgcn_mfma_f32_16x16x32_bf16(af[i], bfr[j], acc[i][j], 0, 0, 0);
        }
        cur ^= 1;
    }
#undef STAGE_OUT

#pragma unroll
    for (int i = 0; i < 2; i++)
#pragma unroll
        for (int j = 0; j < 4; j++)
#pragma unroll
            for (int r = 0; r < 4; r++) {
                const int row = m0 + wm + i * 16 + quad * 4 + r;
                const int col = n0 + wn + j * 16 + l15;
                C[(size_t)row * 1024 + col] = acc[i][j][r];
            }
}

// Flash attention, causal — round-13 kernel RESTORED (verified 59.6us):
// per-wave LDS regions for K AND V, no block barriers in loop, counted
// per-wave vmcnt, MEMFENCE group pinning, pkbf2f packs, T5 setprio around
// MFMA clusters. V-direct-to-register experiments (rounds 14/15) are closed:
// V register prefetch spills at any usable occupancy — V must stage through
// zero-VGPR global_load_lds.
// Scheme per wave:
//   STAGE_K(kp+1) | vmcnt(8) [K(kp) ready] | QK+softmax
//   | vmcnt(4) [V(kp) ready] | PV | STAGE_V(kp+1).
// K dbuf 8KB/wave + V single-buf 4KB/wave = 48KB/block -> 3 blocks/CU.
// Q (pre-scaled by 1/8*log2e), K: [H][S][64] bf16. Vt: [H][64][S] bf16.
// Y: [S][DMODEL] bf16.
__global__ __launch_bounds__(256, 3) void attn(const u16* __restrict__ Q,
                                               const u16* __restrict__ Kh,
                                               const u16* __restrict__ Vt,
                                               u16* __restrict__ Y) {
    __shared__ __align__(16) u16 KW[2][4][2048];  // 32KB: per-wave K pair dbuf
    __shared__ __align__(16) u16 VW[4][2048];     // 16KB: per-wave V pair single-buf
    const int b = blockIdx.x;
    const int head = b & 15;                      // head pinned to XCD (b%8)
    const int jq = 63 - (b >> 4);                 // longest q-tile first
    const int nkt = jq + 1;                       // 64-key tiles this block needs
    const int np = (nkt + 1) >> 1;                // key-tile PAIRS (incl. odd tail)
    const int qa = jq * 64;
    const int tid = threadIdx.x, lane = tid & 63, w = tid >> 6;
    const int l15 = lane & 15, quad = lane >> 4;
    const int swz = l15 & 7;

    const u16* Qp = Q + (size_t)head * S_LEN * 64;
    const u16* Kp = Kh + (size_t)head * S_LEN * 64;
    const u16* Vp = Vt + (size_t)head * 64 * S_LEN;

    // Q fragments: all 64 q-rows in registers (B-operand: n=l15 row, k=quad*8 dims)
    bf16x8 qf[4][2];
#pragma unroll
    for (int qg = 0; qg < 4; qg++)
#pragma unroll
        for (int h = 0; h < 2; h++)
            qf[qg][h] = *(const bf16x8*)(Qp + (size_t)(qa + qg * 16 + l15) * 64 + h * 32 + quad * 8);
    MEMFENCE;   // qf loads are the oldest VMEM group

    f32x4 o[4][4];   // o[dg][qg]: dim = dg*16+quad*4+r, qrow = qg*16+l15
#pragma unroll
    for (int dg = 0; dg < 4; dg++)
#pragma unroll
        for (int qg = 0; qg < 4; qg++) o[dg][qg] = (f32x4){0.f, 0.f, 0.f, 0.f};
    float lp[4] = {0.f, 0.f, 0.f, 0.f};

    const int keyl = w * 16 + quad * 4;           // key-in-tile of this lane's 4 scores
    // V read offsets (u16): 16B-chunk swizzle P = L ^ ((d>>1)&3), d&~15 == dg*16
    const int s4 = (l15 >> 1) & 3;
    const int ceo = (((quad >> 1) ^ s4)) * 8 + (quad & 1) * 4;  // even-tile u64
    const int coo = ceo ^ 16;                                   // odd-tile u64 (chunk^2)

    union PU { u32 d[4]; bf16x8 v; };
    union VU { u64 d[2]; bf16x8 v; };

// Per-wave K stage: one PAIR stripe (rows 0-15 even tile, 16-31 odd), 4 cp16.
// LDS linear (base + lane*16); swizzle via global source: logchunk = (lane&7)^(lane>>3).
#define STAGE_K(buf, kp2)                                                               \
    {                                                                                   \
        _Pragma("unroll")                                                               \
        for (int i = 0; i < 4; i++) {                                                   \
            const int gk = (kp2) * 128 + w * 16 + (i & 1) * 8 + (lane >> 3) + (i >> 1) * 64; \
            const int lc = (lane & 7) ^ (lane >> 3);                                    \
            cp16(Kp + (size_t)gk * 64 + lc * 8, KW[buf][w] + i * 512 + lane * 8);       \
        }                                                                               \
    }

// Per-wave V stage: 64 dims x 32 keys (16 even + 16 odd), 4 cp16.
// Phys chunk lane&3 holds logical L = (lane&3)^((lane>>3)&3);
// L<2 -> even keys L*8.., L>=2 -> odd keys (L-2)*8..
#define STAGE_V(kp2)                                                                    \
    {                                                                                   \
        _Pragma("unroll")                                                               \
        for (int i = 0; i < 4; i++) {                                                   \
            const int d = i * 16 + (lane >> 2);                                         \
            const int L = (lane & 3) ^ ((lane >> 3) & 3);                               \
            const int s = (kp2) * 128 + w * 16 + (L >> 1) * 64 + (L & 1) * 8;           \
            cp16(Vp + (size_t)d * S_LEN + s, VW[w] + i * 512 + lane * 8);               \
        }                                                                               \
    }

#define QK_PHASE(DGE, DGO, HO)                                                          \
    {                                                                                   \
        const u16* Kb = KW[cur][w];                                                     \
        const bf16x8 kE0 = *(const bf16x8*)(Kb + l15 * 64 + (quad ^ swz) * 8);          \
        const bf16x8 kE1 = *(const bf16x8*)(Kb + l15 * 64 + ((4 ^ quad) ^ swz) * 8);    \
        const bf16x8 kO0 = *(const bf16x8*)(Kb + (16 + l15) * 64 + (quad ^ swz) * 8);   \
        const bf16x8 kO1 = *(const bf16x8*)(Kb + (16 + l15) * 64 + ((4 ^ quad) ^ swz) * 8); \
        __builtin_amdgcn_s_setprio(1);                                                  \
        _Pragma("unroll")                                                               \
        for (int qg = 0; qg < 4; qg++) {                                                \
            const int ql = qg * 16 + l15;                                               \
            f32x4 c = (f32x4){0.f, 0.f, 0.f, 0.f};                                      \
            c = __builtin_amdgcn_mfma_f32_16x16x32_bf16(kE0, qf[qg][0], c, 0, 0, 0);    \
            c = __builtin_amdgcn_mfma_f32_16x16x32_bf16(kE1, qf[qg][1], c, 0, 0, 0);    \
            float p0 = __builtin_amdgcn_exp2f(c[0]);                                    \
            float p1 = __builtin_amdgcn_exp2f(c[1]);                                    \
            float p2 = __builtin_amdgcn_exp2f(c[2]);                                    \
            float p3 = __builtin_amdgcn_exp2f(c[3]);                                    \
            if (DGE) {                                                                  \
                if (keyl + 0 > ql) p0 = 0.f;                                            \
                if (keyl + 1 > ql) p1 = 0.f;                                            \
                if (keyl + 2 > ql) p2 = 0.f;                                            \
                if (keyl + 3 > ql) p3 = 0.f;                                            \
            }                                                                           \
            lp[qg] += (p0 + p1) + (p2 + p3);                                            \
            pu[qg].d[0] = pkbf2f(p0, p1);                                               \
            pu[qg].d[1] = pkbf2f(p2, p3);                                               \
            if (HO) {                                                                   \
                f32x4 cc = (f32x4){0.f, 0.f, 0.f, 0.f};                                 \
                cc = __builtin_amdgcn_mfma_f32_16x16x32_bf16(kO0, qf[qg][0], cc, 0, 0, 0); \
                cc = __builtin_amdgcn_mfma_f32_16x16x32_bf16(kO1, qf[qg][1], cc, 0, 0, 0); \
                float q0 = __builtin_amdgcn_exp2f(cc[0]);                               \
                float q1 = __builtin_amdgcn_exp2f(cc[1]);                               \
                float q2 = __builtin_amdgcn_exp2f(cc[2]);                               \
                float q3 = __builtin_amdgcn_exp2f(cc[3]);                               \
                if (DGO) {                                                              \
                    if (keyl + 0 > ql) q0 = 0.f;                                        \
                    if (keyl + 1 > ql) q1 = 0.f;                                        \
                    if (keyl + 2 > ql) q2 = 0.f;                                        \
                    if (keyl + 3 > ql) q3 = 0.f;                                        \
                }                                                                       \
                lp[qg] += (q0 + q1) + (q2 + q3);                                        \
                pu[qg].d[2] = pkbf2f(q0, q1);                                           \
                pu[qg].d[3] = pkbf2f(q2, q3);                                           \
            } else {                                                                    \
                pu[qg].d[2] = 0u; pu[qg].d[3] = 0u;                                     \
            }                                                                           \
        }                                                                               \
        __builtin_amdgcn_s_setprio(0);                                                  \
    }

#define PV_PHASE()                                                                      \
    {                                                                                   \
        __builtin_amdgcn_s_setprio(1);                                                  \
        _Pragma("unroll")                                                               \
        for (int dg = 0; dg < 4; dg++) {                                                \
            const u16* vb = VW[w] + (dg * 16 + l15) * 32;                               \
            VU vf;                                                                      \
            vf.d[0] = *(const u64*)(vb + ceo);                                          \
            vf.d[1] = *(const u64*)(vb + coo);                                          \
            _Pragma("unroll")                                                           \
            for (int qg = 0; qg < 4; qg++)                                              \
                o[dg][qg] = __builtin_amdgcn_mfma_f32_16x16x32_bf16(vf.v, pu[qg].v, o[dg][qg], 0, 0, 0); \
        }                                                                               \
        __builtin_amdgcn_s_setprio(0);                                                  \
    }

    // prologue: K(0) then V(0), each group fenced (oldest-first order is load-bearing)
    STAGE_K(0, 0);
    MEMFENCE;
    STAGE_V(0);
    MEMFENCE;

    int cur = 0;
    // main loop: all pairs strictly below the diagonal pair (no masks, hasO always)
    for (int kp = 0; kp < np - 1; kp++) {
        STAGE_K(cur ^ 1, kp + 1);                      // group: 4 cp16 in flight
        asm volatile("s_waitcnt vmcnt(8)" ::: "memory");   // K(kp) landed; V(kp)+K(kp+1) in flight
        __builtin_amdgcn_sched_barrier(0);
        PU pu[4];
        QK_PHASE(false, false, true);
        asm volatile("s_waitcnt vmcnt(4)" ::: "memory");   // V(kp) landed; K(kp+1) in flight
        __builtin_amdgcn_sched_barrier(0);
        PV_PHASE();
        MEMFENCE;                                      // PV ds_reads precede V restage
        STAGE_V(kp + 1);
        MEMFENCE;                                      // V group cannot mix with next K group
        cur ^= 1;
    }
    // diagonal (last) pair: jq even -> masked even tile only; jq odd -> masked odd tile
    {
        asm volatile("s_waitcnt vmcnt(4)" ::: "memory");   // K(last) landed; V(last) in flight
        __builtin_amdgcn_sched_barrier(0);
        const bool dE = !(jq & 1);
        const bool hO = (jq & 1);
        PU pu[4];
        QK_PHASE(dE, true, hO);
        asm volatile("s_waitcnt vmcnt(0)" ::: "memory");   // V(last) landed
        __builtin_amdgcn_sched_barrier(0);
        PV_PHASE();
    }
#undef STAGE_K
#undef STAGE_V
#undef QK_PHASE
#undef PV_PHASE

    // ---- epilogue: cross-wave reduction of l and o, normalize, store ----
    // OR/LR overlay the (dead) KW buffers; all DMA drained (vmcnt(0) above),
    // barrier before overlay.
    float* OR = (float*)&KW[0][0][0];                   // 20.5KB padded o-partials
    float* LR = (float*)((char*)&KW[0][0][0] + 24576);  // 1KB l-partials
#pragma unroll
    for (int qg = 0; qg < 4; qg++) {
        lp[qg] += __shfl_xor(lp[qg], 16);
        lp[qg] += __shfl_xor(lp[qg], 32);
    }
    __syncthreads();                       // all waves done with their regions
    if (lane < 16) {
#pragma unroll
        for (int qg = 0; qg < 4; qg++) LR[(w * 4 + qg) * 16 + lane] = lp[qg];
    }
    const int qrow = tid >> 2;               // this thread reduces (qrow, 4 dims)
    const int qgr = qrow >> 4, lq = qrow & 15;
    const int dpart = (tid & 3) * 4;
    __syncthreads();
    const float lsum = LR[qgr * 16 + lq] + LR[(4 + qgr) * 16 + lq] +
                       LR[(8 + qgr) * 16 + lq] + LR[(12 + qgr) * 16 + lq];
    const float inv = 1.f / lsum;
#pragma unroll
    for (int dg = 0; dg < 4; dg++) {
        if (dg) __syncthreads();             // prev pass reads done before overwrite
#pragma unroll
        for (int qg = 0; qg < 4; qg++)
            *(f32x4*)&OR[((w * 4 + qg) * 16 + l15) * 20 + quad * 4] = o[dg][qg];
        __syncthreads();
        f32x4 s = (f32x4){0.f, 0.f, 0.f, 0.f};
#pragma unroll
        for (int sw = 0; sw < 4; sw++)
            s += *(const f32x4*)&OR[((sw * 4 + qgr) * 16 + lq) * 20 + dpart];
        const u32 y0 = pkbf2(s[0] * inv, s[1] * inv);
        const u32 y1 = pkbf2(s[2] * inv, s[3] * inv);
        *(u64*)(Y + (size_t)(qa + qrow) * DMODEL + head * 64 + dg * 16 + dpart) =
            (u64)y0 | ((u64)y1 << 32);
    }
}

extern "C" void kernel_launch(void* const* d_in, const int* in_sizes, int n_in,
                              void* d_out, int out_size, void* d_ws, size_t ws_size,
                              hipStream_t stream) {
    const float* x  = (const float*)d_in[0];
    const float* wq = (const float*)d_in[1];
    const float* wk = (const float*)d_in[2];
    const float* wv = (const float*)d_in[3];
    const float* wo = (const float*)d_in[4];
    float* out = (float*)d_out;

    u16* qh  = (u16*)d_ws;                            // [0,8) MB
    u16* kh  = qh + (size_t)S_LEN * DMODEL;           // [8,16)
    u16* vt  = kh + (size_t)S_LEN * DMODEL;           // [16,24)
    u16* xb  = vt + (size_t)S_LEN * DMODEL;           // [24,32) x bf16, later y
    u16* y   = xb;                                    // alias after QKV proj
    u16* wb3 = xb + (size_t)S_LEN * DMODEL;           // [32,38) [wq;wk;wv]
    u16* wob = wb3 + (size_t)3 * DMODEL * DMODEL;     // [38,40) wo bf16

    const dim3 blk(256);

    cvt_all<<<4096, blk, 0, stream>>>(x, wq, wk, wv, wo, xb, wb3, wob);
    gemm_qkv<<<dim3(3 * DMODEL / 128, S_LEN / 128), blk, 0, stream>>>(xb, wb3, qh, kh, vt);
    attn<<<1024, blk, 0, stream>>>(qh, kh, vt, y);
    gemm_out<<<512, blk, 0, stream>>>(y, wob, out);
}

// Round 17
// 190.642 us; speedup vs baseline: 2.2180x; 1.0685x over previous
//
#include <hip/hip_runtime.h>

#define S_LEN 4096
#define DMODEL 1024
#define NHEADS 16

typedef __attribute__((ext_vector_type(8))) short bf16x8;
typedef __attribute__((ext_vector_type(4))) float f32x4;
typedef unsigned short u16;
typedef unsigned int u32;
typedef unsigned long long u64;

// IR+MIR memory fence: pins global_load_lds issue order at group granularity.
#define MEMFENCE asm volatile("" ::: "memory")

__device__ inline u16 f2bf(float f) {
    union { float f; u32 u; } v; v.f = f;
    u32 r = v.u + 0x7fffu + ((v.u >> 16) & 1u);
    return (u16)(r >> 16);
}

// exact RNE pack (epilogues)
__device__ inline u32 pkbf2(float a, float b) {
    union { float f; u32 u; } ua, ub; ua.f = a; ub.f = b;
    const u32 ra = ua.u + 0x7fffu + ((ua.u >> 16) & 1u);
    const u32 rb = ub.u + 0x7fffu + ((ub.u >> 16) & 1u);
    return __builtin_amdgcn_perm(rb, ra, 0x07060302u);
}

// fast pack: round-half-up (3 VALU ops). Differs from RNE only at exact ties.
// NOTE: v_cvt_pk_bf16_f32 inline-asm failed correctness twice (rounds 7,9);
// keep pkbf2f.
__device__ inline u32 pkbf2f(float a, float b) {
    union { float f; u32 u; } ua, ub; ua.f = a; ub.f = b;
    const u32 ra = ua.u + 0x8000u;
    const u32 rb = ub.u + 0x8000u;
    return __builtin_amdgcn_perm(rb, ra, 0x07060302u);
}

// async 16B global->LDS DMA. LDS dst = wave-uniform base + lane*16 at all sites.
__device__ inline void cp16(const void* g, void* l) {
    __builtin_amdgcn_global_load_lds(
        (const __attribute__((address_space(1))) unsigned int*)g,
        (__attribute__((address_space(3))) unsigned int*)l, 16, 0, 0);
}

// One launch converts x (4M), wq/wk/wv (-> w3 contiguous), wo (-> wob). 4096 blocks.
__global__ __launch_bounds__(256) void cvt_all(const float* __restrict__ x,
                                               const float* __restrict__ wq,
                                               const float* __restrict__ wk,
                                               const float* __restrict__ wv,
                                               const float* __restrict__ wo,
                                               u16* __restrict__ xb,
                                               u16* __restrict__ w3,
                                               u16* __restrict__ wob) {
    const int b = blockIdx.x;
    const float* s; u16* d; int off;
    const int NW = DMODEL * DMODEL;  // 1M
    if (b < 2048)      { s = x;  d = xb;          off = b * 2048; }
    else if (b < 2560) { s = wq; d = w3;          off = (b - 2048) * 2048; }
    else if (b < 3072) { s = wk; d = w3 + NW;     off = (b - 2560) * 2048; }
    else if (b < 3584) { s = wv; d = w3 + 2 * NW; off = (b - 3072) * 2048; }
    else               { s = wo; d = wob;         off = (b - 3584) * 2048; }
    const int i = off + threadIdx.x * 8;
    const float4 a = *(const float4*)(s + i);
    const float4 c = *(const float4*)(s + i + 4);
    u16 t[8];
    t[0] = f2bf(a.x); t[1] = f2bf(a.y); t[2] = f2bf(a.z); t[3] = f2bf(a.w);
    t[4] = f2bf(c.x); t[5] = f2bf(c.y); t[6] = f2bf(c.z); t[7] = f2bf(c.w);
    *(bf16x8*)(d + i) = *(const bf16x8*)t;
}

// Fused QKV projection: C = x(4096x1024) * W3^T (W3 = [wq;wk;wv] 3072x1024).
// Round-17: 128(M) x 192(N) TILE — 1.5x MFMA per barrier window (24 vs 16
// per wave per step) to amortize the fixed per-step cost (round-11 PMC:
// MfmaUtil 16%, 57% dead cycles; round-12 proved deeper lookahead null ->
// the fix is density, not latency). Grid 16x32 = 512 = exactly 2 blocks/CU
// (perfect balance); LDS 3buf x (8KB A + 12KB B) = 60KB caps at 2/CU;
// __launch_bounds__(256,2) (~170 regs <= 256, no spill). Verified 3-buffer
// counted-vmcnt raw-barrier skeleton retained; stage group = 5 cp16 ->
// vmcnt(5). 192 straddles the 1024 Q/K/V boundaries -> epilogue dispatches
// `which` per 16-wide j-fragment (16-aligned -> wave-uniform, no diverge);
// store forms unchanged (coalesced scalar Q/K, u64 V^T).
// Q pre-scaled by 1/8*log2e. Q,K -> [h][m][c]; V -> [h][c][m].
__global__ __launch_bounds__(256, 2) void gemm_qkv(const u16* __restrict__ A,
                                                   const u16* __restrict__ B3,
                                                   u16* __restrict__ Qo,
                                                   u16* __restrict__ Ko,
                                                   u16* __restrict__ Vo) {
    __shared__ __align__(16) u16 As[3][128 * 32];   // 24KB
    __shared__ __align__(16) u16 Bs[3][192 * 32];   // 36KB
    const int tid = threadIdx.x, lane = tid & 63, wave = tid >> 6;
    const int wm = (wave >> 1) * 64, wn = (wave & 1) * 96;
    const int m0 = blockIdx.y * 128, n0 = blockIdx.x * 192;
    const int l15 = lane & 15, quad = lane >> 4;

    f32x4 acc[4][6];
#pragma unroll
    for (int i = 0; i < 4; i++)
#pragma unroll
        for (int j = 0; j < 6; j++) acc[i][j] = (f32x4){0.f, 0.f, 0.f, 0.f};

    const int r0 = tid >> 2, c0 = (tid & 3) * 8;

// one K-step stage (20KB = 5 cp16/thread) into buffer `buf`
#define STAGE_QKV(buf, kkb)                                                        \
    {                                                                              \
        cp16(A + (size_t)(m0 + r0) * 1024 + (kkb) + c0,        As[buf] + r0 * 32 + c0); \
        cp16(A + (size_t)(m0 + r0 + 64) * 1024 + (kkb) + c0,   As[buf] + (r0 + 64) * 32 + c0); \
        cp16(B3 + (size_t)(n0 + r0) * 1024 + (kkb) + c0,       Bs[buf] + r0 * 32 + c0); \
        cp16(B3 + (size_t)(n0 + r0 + 64) * 1024 + (kkb) + c0,  Bs[buf] + (r0 + 64) * 32 + c0); \
        cp16(B3 + (size_t)(n0 + r0 + 128) * 1024 + (kkb) + c0, Bs[buf] + (r0 + 128) * 32 + c0); \
    }

#define COMPUTE_QKV(cur)                                                           \
    {                                                                              \
        bf16x8 af[4], bfr[6];                                                      \
        _Pragma("unroll")                                                          \
        for (int i = 0; i < 4; i++)                                                \
            af[i] = *(const bf16x8*)(As[cur] + (wm + i * 16 + l15) * 32 + quad * 8); \
        _Pragma("unroll")                                                          \
        for (int j = 0; j < 6; j++)                                                \
            bfr[j] = *(const bf16x8*)(Bs[cur] + (wn + j * 16 + l15) * 32 + quad * 8); \
        _Pragma("unroll")                                                          \
        for (int i = 0; i < 4; i++)                                                \
            _Pragma("unroll")                                                      \
            for (int j = 0; j < 6; j++)                                            \
                acc[i][j] = __builtin_amdgcn_mfma_f32_16x16x32_bf16(af[i], bfr[j], acc[i][j], 0, 0, 0); \
    }

    // prologue: 2 stages in flight (10 cp16/thread)
    STAGE_QKV(0, 0);
    MEMFENCE;
    STAGE_QKV(1, 32);
    MEMFENCE;

    // main loop: 31 steps with counted wait (stage k+1 stays in flight)
    for (int ks = 0; ks < 31; ks++) {
        asm volatile("s_waitcnt vmcnt(5)" ::: "memory");  // my stage(ks) landed
        __builtin_amdgcn_s_barrier();                     // everyone's stage(ks) landed
        __builtin_amdgcn_sched_barrier(0);
        if (ks < 30) {
            STAGE_QKV((ks + 2) % 3, (ks + 2) * 32);       // 2 steps of latency cover
            MEMFENCE;
        }
        COMPUTE_QKV(ks % 3);
    }
    // tail step 31: drain and compute
    asm volatile("s_waitcnt vmcnt(0)" ::: "memory");
    __builtin_amdgcn_s_barrier();
    __builtin_amdgcn_sched_barrier(0);
    COMPUTE_QKV(1);                                       // 31 % 3 == 1
#undef STAGE_QKV
#undef COMPUTE_QKV

    // epilogue: per-j `which` dispatch (16-wide frags are 16-aligned -> uniform)
    const int colbase = n0 + wn;
#pragma unroll
    for (int j = 0; j < 6; j++) {
        const int col = colbase + j * 16 + l15;
        const int which = col >> 10;
        const int cr = col & 1023;
        const int h = cr >> 6, c = cr & 63;
        u16* dst = (which == 0) ? Qo : (which == 1) ? Ko : Vo;
        u16* base = dst + (size_t)h * S_LEN * 64;
        if (which < 2) {
            // coalesced scalar stores: quarter-wave (l15) = 16 consecutive cols (32B)
            const float sc = (which == 0) ? 0.125f * 1.4426950408889634f : 1.0f;
#pragma unroll
            for (int i = 0; i < 4; i++) {
#pragma unroll
                for (int r = 0; r < 4; r++) {
                    const int row = m0 + wm + i * 16 + quad * 4 + r;
                    base[(size_t)row * 64 + c] = f2bf(acc[i][j][r] * sc);
                }
            }
        } else {
            // V^T: r=0..3 are 4 consecutive u16 in memory -> u64 store
#pragma unroll
            for (int i = 0; i < 4; i++) {
                const int row0 = m0 + wm + i * 16 + quad * 4;
                const u32 y0 = pkbf2(acc[i][j][0], acc[i][j][1]);
                const u32 y1 = pkbf2(acc[i][j][2], acc[i][j][3]);
                *(u64*)(base + (size_t)c * S_LEN + row0) = (u64)y0 | ((u64)y1 << 32);
            }
        }
    }
}

// Output projection: C(fp32 [4096][1024]) = y(bf16) * wo^T. Split-M:
// 64x128 tiles, grid 512 (2/CU), BK=64, dbuf single-barrier, swizzled LDS,
// plain coalesced fp32 stores (round-8 form, verified).
__global__ __launch_bounds__(256) void gemm_out(const u16* __restrict__ A,
                                                const u16* __restrict__ B,
                                                float* __restrict__ C) {
    __shared__ __align__(16) u16 As[2][64 * 64];    // swizzled [row][col]
    __shared__ __align__(16) u16 Bs[2][128 * 64];   // swizzled [row][col]
    const int tid = threadIdx.x, lane = tid & 63, wave = tid >> 6;
    const int wm = (wave >> 1) * 32, wn = (wave & 1) * 64;
    const int bx = blockIdx.x;
    const int n0 = (bx & 7) * 128, m0 = (bx >> 3) * 64;
    const int l15 = lane & 15, quad = lane >> 4;
    const int swz = l15 & 7;

    f32x4 acc[2][4];
#pragma unroll
    for (int i = 0; i < 2; i++)
#pragma unroll
        for (int j = 0; j < 4; j++) acc[i][j] = (f32x4){0.f, 0.f, 0.f, 0.f};

#define STAGE_OUT(buf, kb)                                                              \
    {                                                                                   \
        _Pragma("unroll")                                                               \
        for (int q = 0; q < 2; q++) {                                                   \
            const int ch = tid + q * 256;                                               \
            const int ar = ch >> 3, ac = ((ch & 7) ^ (ar & 7)) * 8;                     \
            cp16(A + (size_t)(m0 + ar) * 1024 + (kb) + ac, As[buf] + ch * 8);           \
        }                                                                               \
        _Pragma("unroll")                                                               \
        for (int q = 0; q < 4; q++) {                                                   \
            const int ch = tid + q * 256;                                               \
            const int br = ch >> 3, bc = ((ch & 7) ^ (br & 7)) * 8;                     \
            cp16(B + (size_t)(n0 + br) * 1024 + (kb) + bc, Bs[buf] + ch * 8);           \
        }                                                                               \
    }

    STAGE_OUT(0, 0);
    int cur = 0;
    for (int kk = 0; kk < 1024; kk += 64) {
        __syncthreads();  // drains vmcnt(0): buf[cur] ready, buf[cur^1] reads done
        if (kk + 64 < 1024) STAGE_OUT(cur ^ 1, kk + 64);
#pragma unroll
        for (int h = 0; h < 2; h++) {
            const int cc = (h * 4 + quad) ^ swz;
            bf16x8 af[2], bfr[4];
#pragma unroll
            for (int i = 0; i < 2; i++)
                af[i] = *(const bf16x8*)(As[cur] + (wm + i * 16 + l15) * 64 + cc * 8);
#pragma unroll
            for (int j = 0; j < 4; j++)
                bfr[j] = *(const bf16x8*)(Bs[cur] + (wn + j * 16 + l15) * 64 + cc * 8);
#pragma unroll
            for (int i = 0; i < 2; i++)
#pragma unroll
                for (int j = 0; j < 4; j++)
                    acc[i][j] = __builtin_amdgcn_mfma_f32_16x16x32_bf16(af[i], bfr[j], acc[i][j], 0, 0, 0);
        }
        cur ^= 1;
    }
#undef STAGE_OUT

#pragma unroll
    for (int i = 0; i < 2; i++)
#pragma unroll
        for (int j = 0; j < 4; j++)
#pragma unroll
            for (int r = 0; r < 4; r++) {
                const int row = m0 + wm + i * 16 + quad * 4 + r;
                const int col = n0 + wn + j * 16 + l15;
                C[(size_t)row * 1024 + col] = acc[i][j][r];
            }
}

// Flash attention, causal — round-13 kernel (verified 59.6-61us):
// per-wave LDS regions for K AND V, no block barriers in loop, counted
// per-wave vmcnt, MEMFENCE group pinning, pkbf2f packs, T5 setprio around
// MFMA clusters. V-direct-to-register is closed (spills at any usable
// occupancy) — V must stage through zero-VGPR global_load_lds.
// Scheme per wave:
//   STAGE_K(kp+1) | vmcnt(8) [K(kp) ready] | QK+softmax
//   | vmcnt(4) [V(kp) ready] | PV | STAGE_V(kp+1).
// K dbuf 8KB/wave + V single-buf 4KB/wave = 48KB/block -> 3 blocks/CU.
// Q (pre-scaled by 1/8*log2e), K: [H][S][64] bf16. Vt: [H][64][S] bf16.
// Y: [S][DMODEL] bf16.
__global__ __launch_bounds__(256, 3) void attn(const u16* __restrict__ Q,
                                               const u16* __restrict__ Kh,
                                               const u16* __restrict__ Vt,
                                               u16* __restrict__ Y) {
    __shared__ __align__(16) u16 KW[2][4][2048];  // 32KB: per-wave K pair dbuf
    __shared__ __align__(16) u16 VW[4][2048];     // 16KB: per-wave V pair single-buf
    const int b = blockIdx.x;
    const int head = b & 15;                      // head pinned to XCD (b%8)
    const int jq = 63 - (b >> 4);                 // longest q-tile first
    const int nkt = jq + 1;                       // 64-key tiles this block needs
    const int np = (nkt + 1) >> 1;                // key-tile PAIRS (incl. odd tail)
    const int qa = jq * 64;
    const int tid = threadIdx.x, lane = tid & 63, w = tid >> 6;
    const int l15 = lane & 15, quad = lane >> 4;
    const int swz = l15 & 7;

    const u16* Qp = Q + (size_t)head * S_LEN * 64;
    const u16* Kp = Kh + (size_t)head * S_LEN * 64;
    const u16* Vp = Vt + (size_t)head * 64 * S_LEN;

    // Q fragments: all 64 q-rows in registers (B-operand: n=l15 row, k=quad*8 dims)
    bf16x8 qf[4][2];
#pragma unroll
    for (int qg = 0; qg < 4; qg++)
#pragma unroll
        for (int h = 0; h < 2; h++)
            qf[qg][h] = *(const bf16x8*)(Qp + (size_t)(qa + qg * 16 + l15) * 64 + h * 32 + quad * 8);
    MEMFENCE;   // qf loads are the oldest VMEM group

    f32x4 o[4][4];   // o[dg][qg]: dim = dg*16+quad*4+r, qrow = qg*16+l15
#pragma unroll
    for (int dg = 0; dg < 4; dg++)
#pragma unroll
        for (int qg = 0; qg < 4; qg++) o[dg][qg] = (f32x4){0.f, 0.f, 0.f, 0.f};
    float lp[4] = {0.f, 0.f, 0.f, 0.f};

    const int keyl = w * 16 + quad * 4;           // key-in-tile of this lane's 4 scores
    // V read offsets (u16): 16B-chunk swizzle P = L ^ ((d>>1)&3), d&~15 == dg*16
    const int s4 = (l15 >> 1) & 3;
    const int ceo = (((quad >> 1) ^ s4)) * 8 + (quad & 1) * 4;  // even-tile u64
    const int coo = ceo ^ 16;                                   // odd-tile u64 (chunk^2)

    union PU { u32 d[4]; bf16x8 v; };
    union VU { u64 d[2]; bf16x8 v; };

// Per-wave K stage: one PAIR stripe (rows 0-15 even tile, 16-31 odd), 4 cp16.
// LDS linear (base + lane*16); swizzle via global source: logchunk = (lane&7)^(lane>>3).
#define STAGE_K(buf, kp2)                                                               \
    {                                                                                   \
        _Pragma("unroll")                                                               \
        for (int i = 0; i < 4; i++) {                                                   \
            const int gk = (kp2) * 128 + w * 16 + (i & 1) * 8 + (lane >> 3) + (i >> 1) * 64; \
            const int lc = (lane & 7) ^ (lane >> 3);                                    \
            cp16(Kp + (size_t)gk * 64 + lc * 8, KW[buf][w] + i * 512 + lane * 8);       \
        }                                                                               \
    }

// Per-wave V stage: 64 dims x 32 keys (16 even + 16 odd), 4 cp16.
// Phys chunk lane&3 holds logical L = (lane&3)^((lane>>3)&3);
// L<2 -> even keys L*8.., L>=2 -> odd keys (L-2)*8..
#define STAGE_V(kp2)                                                                    \
    {                                                                                   \
        _Pragma("unroll")                                                               \
        for (int i = 0; i < 4; i++) {                                                   \
            const int d = i * 16 + (lane >> 2);                                         \
            const int L = (lane & 3) ^ ((lane >> 3) & 3);                               \
            const int s = (kp2) * 128 + w * 16 + (L >> 1) * 64 + (L & 1) * 8;           \
            cp16(Vp + (size_t)d * S_LEN + s, VW[w] + i * 512 + lane * 8);               \
        }                                                                               \
    }

#define QK_PHASE(DGE, DGO, HO)                                                          \
    {                                                                                   \
        const u16* Kb = KW[cur][w];                                                     \
        const bf16x8 kE0 = *(const bf16x8*)(Kb + l15 * 64 + (quad ^ swz) * 8);          \
        const bf16x8 kE1 = *(const bf16x8*)(Kb + l15 * 64 + ((4 ^ quad) ^ swz) * 8);    \
        const bf16x8 kO0 = *(const bf16x8*)(Kb + (16 + l15) * 64 + (quad ^ swz) * 8);   \
        const bf16x8 kO1 = *(const bf16x8*)(Kb + (16 + l15) * 64 + ((4 ^ quad) ^ swz) * 8); \
        __builtin_amdgcn_s_setprio(1);                                                  \
        _Pragma("unroll")                                                               \
        for (int qg = 0; qg < 4; qg++) {                                                \
            const int ql = qg * 16 + l15;                                               \
            f32x4 c = (f32x4){0.f, 0.f, 0.f, 0.f};                                      \
            c = __builtin_amdgcn_mfma_f32_16x16x32_bf16(kE0, qf[qg][0], c, 0, 0, 0);    \
            c = __builtin_amdgcn_mfma_f32_16x16x32_bf16(kE1, qf[qg][1], c, 0, 0, 0);    \
            float p0 = __builtin_amdgcn_exp2f(c[0]);                                    \
            float p1 = __builtin_amdgcn_exp2f(c[1]);                                    \
            float p2 = __builtin_amdgcn_exp2f(c[2]);                                    \
            float p3 = __builtin_amdgcn_exp2f(c[3]);                                    \
            if (DGE) {                                                                  \
                if (keyl + 0 > ql) p0 = 0.f;                                            \
                if (keyl + 1 > ql) p1 = 0.f;                                            \
                if (keyl + 2 > ql) p2 = 0.f;                                            \
                if (keyl + 3 > ql) p3 = 0.f;                                            \
            }                                                                           \
            lp[qg] += (p0 + p1) + (p2 + p3);                                            \
            pu[qg].d[0] = pkbf2f(p0, p1);                                               \
            pu[qg].d[1] = pkbf2f(p2, p3);                                               \
            if (HO) {                                                                   \
                f32x4 cc = (f32x4){0.f, 0.f, 0.f, 0.f};                                 \
                cc = __builtin_amdgcn_mfma_f32_16x16x32_bf16(kO0, qf[qg][0], cc, 0, 0, 0); \
                cc = __builtin_amdgcn_mfma_f32_16x16x32_bf16(kO1, qf[qg][1], cc, 0, 0, 0); \
                float q0 = __builtin_amdgcn_exp2f(cc[0]);                               \
                float q1 = __builtin_amdgcn_exp2f(cc[1]);                               \
                float q2 = __builtin_amdgcn_exp2f(cc[2]);                               \
                float q3 = __builtin_amdgcn_exp2f(cc[3]);                               \
                if (DGO) {                                                              \
                    if (keyl + 0 > ql) q0 = 0.f;                                        \
                    if (keyl + 1 > ql) q1 = 0.f;                                        \
                    if (keyl + 2 > ql) q2 = 0.f;                                        \
                    if (keyl + 3 > ql) q3 = 0.f;                                        \
                }                                                                       \
                lp[qg] += (q0 + q1) + (q2 + q3);                                        \
                pu[qg].d[2] = pkbf2f(q0, q1);                                           \
                pu[qg].d[3] = pkbf2f(q2, q3);                                           \
            } else {                                                                    \
                pu[qg].d[2] = 0u; pu[qg].d[3] = 0u;                                     \
            }                                                                           \
        }                                                                               \
        __builtin_amdgcn_s_setprio(0);                                                  \
    }

#define PV_PHASE()                                                                      \
    {                                                                                   \
        __builtin_amdgcn_s_setprio(1);                                                  \
        _Pragma("unroll")                                                               \
        for (int dg = 0; dg < 4; dg++) {                                                \
            const u16* vb = VW[w] + (dg * 16 + l15) * 32;                               \
            VU vf;                                                                      \
            vf.d[0] = *(const u64*)(vb + ceo);                                          \
            vf.d[1] = *(const u64*)(vb + coo);                                          \
            _Pragma("unroll")                                                           \
            for (int qg = 0; qg < 4; qg++)                                              \
                o[dg][qg] = __builtin_amdgcn_mfma_f32_16x16x32_bf16(vf.v, pu[qg].v, o[dg][qg], 0, 0, 0); \
        }                                                                               \
        __builtin_amdgcn_s_setprio(0);                                                  \
    }

    // prologue: K(0) then V(0), each group fenced (oldest-first order is load-bearing)
    STAGE_K(0, 0);
    MEMFENCE;
    STAGE_V(0);
    MEMFENCE;

    int cur = 0;
    // main loop: all pairs strictly below the diagonal pair (no masks, hasO always)
    for (int kp = 0; kp < np - 1; kp++) {
        STAGE_K(cur ^ 1, kp + 1);                      // group: 4 cp16 in flight
        asm volatile("s_waitcnt vmcnt(8)" ::: "memory");   // K(kp) landed; V(kp)+K(kp+1) in flight
        __builtin_amdgcn_sched_barrier(0);
        PU pu[4];
        QK_PHASE(false, false, true);
        asm volatile("s_waitcnt vmcnt(4)" ::: "memory");   // V(kp) landed; K(kp+1) in flight
        __builtin_amdgcn_sched_barrier(0);
        PV_PHASE();
        MEMFENCE;                                      // PV ds_reads precede V restage
        STAGE_V(kp + 1);
        MEMFENCE;                                      // V group cannot mix with next K group
        cur ^= 1;
    }
    // diagonal (last) pair: jq even -> masked even tile only; jq odd -> masked odd tile
    {
        asm volatile("s_waitcnt vmcnt(4)" ::: "memory");   // K(last) landed; V(last) in flight
        __builtin_amdgcn_sched_barrier(0);
        const bool dE = !(jq & 1);
        const bool hO = (jq & 1);
        PU pu[4];
        QK_PHASE(dE, true, hO);
        asm volatile("s_waitcnt vmcnt(0)" ::: "memory");   // V(last) landed
        __builtin_amdgcn_sched_barrier(0);
        PV_PHASE();
    }
#undef STAGE_K
#undef STAGE_V
#undef QK_PHASE
#undef PV_PHASE

    // ---- epilogue: cross-wave reduction of l and o, normalize, store ----
    // OR/LR overlay the (dead) KW buffers; all DMA drained (vmcnt(0) above),
    // barrier before overlay.
    float* OR = (float*)&KW[0][0][0];                   // 20.5KB padded o-partials
    float* LR = (float*)((char*)&KW[0][0][0] + 24576);  // 1KB l-partials
#pragma unroll
    for (int qg = 0; qg < 4; qg++) {
        lp[qg] += __shfl_xor(lp[qg], 16);
        lp[qg] += __shfl_xor(lp[qg], 32);
    }
    __syncthreads();                       // all waves done with their regions
    if (lane < 16) {
#pragma unroll
        for (int qg = 0; qg < 4; qg++) LR[(w * 4 + qg) * 16 + lane] = lp[qg];
    }
    const int qrow = tid >> 2;               // this thread reduces (qrow, 4 dims)
    const int qgr = qrow >> 4, lq = qrow & 15;
    const int dpart = (tid & 3) * 4;
    __syncthreads();
    const float lsum = LR[qgr * 16 + lq] + LR[(4 + qgr) * 16 + lq] +
                       LR[(8 + qgr) * 16 + lq] + LR[(12 + qgr) * 16 + lq];
    const float inv = 1.f / lsum;
#pragma unroll
    for (int dg = 0; dg < 4; dg++) {
        if (dg) __syncthreads();             // prev pass reads done before overwrite
#pragma unroll
        for (int qg = 0; qg < 4; qg++)
            *(f32x4*)&OR[((w * 4 + qg) * 16 + l15) * 20 + quad * 4] = o[dg][qg];
        __syncthreads();
        f32x4 s = (f32x4){0.f, 0.f, 0.f, 0.f};
#pragma unroll
        for (int sw = 0; sw < 4; sw++)
            s += *(const f32x4*)&OR[((sw * 4 + qgr) * 16 + lq) * 20 + dpart];
        const u32 y0 = pkbf2(s[0] * inv, s[1] * inv);
        const u32 y1 = pkbf2(s[2] * inv, s[3] * inv);
        *(u64*)(Y + (size_t)(qa + qrow) * DMODEL + head * 64 + dg * 16 + dpart) =
            (u64)y0 | ((u64)y1 << 32);
    }
}

extern "C" void kernel_launch(void* const* d_in, const int* in_sizes, int n_in,
                              void* d_out, int out_size, void* d_ws, size_t ws_size,
                              hipStream_t stream) {
    const float* x  = (const float*)d_in[0];
    const float* wq = (const float*)d_in[1];
    const float* wk = (const float*)d_in[2];
    const float* wv = (const float*)d_in[3];
    const float* wo = (const float*)d_in[4];
    float* out = (float*)d_out;

    u16* qh  = (u16*)d_ws;                            // [0,8) MB
    u16* kh  = qh + (size_t)S_LEN * DMODEL;           // [8,16)
    u16* vt  = kh + (size_t)S_LEN * DMODEL;           // [16,24)
    u16* xb  = vt + (size_t)S_LEN * DMODEL;           // [24,32) x bf16, later y
    u16* y   = xb;                                    // alias after QKV proj
    u16* wb3 = xb + (size_t)S_LEN * DMODEL;           // [32,38) [wq;wk;wv]
    u16* wob = wb3 + (size_t)3 * DMODEL * DMODEL;     // [38,40) wo bf16

    const dim3 blk(256);

    cvt_all<<<4096, blk, 0, stream>>>(x, wq, wk, wv, wo, xb, wb3, wob);
    gemm_qkv<<<dim3(3 * DMODEL / 192, S_LEN / 128), blk, 0, stream>>>(xb, wb3, qh, kh, vt);
    attn<<<1024, blk, 0, stream>>>(qh, kh, vt, y);
    gemm_out<<<512, blk, 0, stream>>>(y, wob, out);
}